// Round 1
// baseline (932.208 us; speedup 1.0000x reference)
//
#include <hip/hip_runtime.h>

#define N_NODES 50000
#define N_EDGES 800000
#define N_GRAPHS 128
#define IN_DIM 128
#define HID 256
#define H2 128
#define OUT_DIM 10
#define BN_EPS 1e-5f

// ---------------- degree + normalization ----------------
__global__ void deg_kernel(const int* __restrict__ src, const int* __restrict__ dst,
                           float* __restrict__ outdeg, int* __restrict__ indeg) {
    int e = blockIdx.x * 256 + threadIdx.x;
    if (e < N_EDGES) {
        atomicAdd(&outdeg[src[e]], 1.0f);
        atomicAdd(&indeg[dst[e]], 1);
    }
}

__global__ void dis_kernel(const float* __restrict__ outdeg, const int* __restrict__ indeg,
                           float* __restrict__ out_dis, float* __restrict__ in_dis) {
    int i = blockIdx.x * 256 + threadIdx.x;
    if (i < N_NODES) {
        out_dis[i] = rsqrtf(fmaxf(outdeg[i], 1.0f));
        in_dis[i]  = rsqrtf(fmaxf((float)indeg[i], 1.0f));
    }
}

// ---------------- CSR build: scan + fill ----------------
__global__ __launch_bounds__(1024) void scan_kernel(const int* __restrict__ indeg,
                                                    int* __restrict__ rowptr,
                                                    int* __restrict__ cursor) {
    __shared__ int sums[1024];
    int t = threadIdx.x;
    const int per = (N_NODES + 1023) / 1024;   // 49
    int beg = t * per;
    int end = min(beg + per, N_NODES);
    int s = 0;
    for (int i = beg; i < end; i++) s += indeg[i];
    sums[t] = s;
    __syncthreads();
    for (int off = 1; off < 1024; off <<= 1) {
        int u = (t >= off) ? sums[t - off] : 0;
        __syncthreads();
        sums[t] += u;
        __syncthreads();
    }
    int run = (t == 0) ? 0 : sums[t - 1];
    for (int i = beg; i < end; i++) {
        rowptr[i] = run;
        cursor[i] = run;
        run += indeg[i];
    }
    if (end == N_NODES) rowptr[N_NODES] = sums[1023];
}

__global__ void csr_fill(const int* __restrict__ src, const int* __restrict__ dst,
                         int* __restrict__ cursor, int* __restrict__ csr_src) {
    int e = blockIdx.x * 256 + threadIdx.x;
    if (e < N_EDGES) {
        int pos = atomicAdd(&cursor[dst[e]], 1);
        csr_src[pos] = src[e];
    }
}

// ---------------- pull aggregation (D = 128 always) ----------------
// out[n][c] = in_dis[n] * sum_{e: dst=n} out_dis[src_e] * X[src_e][c]   (+ optional bias,relu)
template<bool EPI>
__global__ __launch_bounds__(128) void pull_agg(const float* __restrict__ X,
        const int* __restrict__ rowptr, const int* __restrict__ csr_src,
        const float* __restrict__ out_dis, const float* __restrict__ in_dis,
        const float* __restrict__ bias, float* __restrict__ out) {
    int n = blockIdx.x;
    int c = threadIdx.x;
    int beg = rowptr[n], end = rowptr[n + 1];
    float acc = 0.f;
    for (int e = beg; e < end; e++) {
        int s = csr_src[e];
        acc += X[(size_t)s * 128 + c] * out_dis[s];
    }
    float v = acc * in_dis[n];
    if (EPI) v = fmaxf(v + bias[c], 0.f);
    out[(size_t)n * 128 + c] = v;
}

// ---------------- register-tiled f32 GEMM: out[M,NOUT] = A[M,K] @ W[K,NOUT] ----------------
template<int K, int NOUT, bool BIASRELU>
__global__ __launch_bounds__(256) void gemm_kernel(const float* __restrict__ A,
        const float* __restrict__ W, const float* __restrict__ bias,
        float* __restrict__ out) {
    constexpr int BM  = 32;
    constexpr int CPT = 8;            // cols per thread
    constexpr int TC  = NOUT / CPT;   // 32 (NOUT=256) or 16 (NOUT=128)
    constexpr int RG  = 256 / TC;     // 8 or 16 row-groups
    constexpr int RPT = BM / RG;      // 4 or 2 rows per thread
    __shared__ float tile[BM][K];

    int row0 = blockIdx.x * BM;
    for (int i = threadIdx.x; i < BM * K; i += 256) {
        int r = i / K, k = i - r * K;
        int row = row0 + r;
        tile[r][k] = (row < N_NODES) ? A[(size_t)row * K + k] : 0.f;
    }
    __syncthreads();

    int tc = threadIdx.x % TC;
    int rg = threadIdx.x / TC;
    float acc[RPT][CPT];
#pragma unroll
    for (int r = 0; r < RPT; r++)
#pragma unroll
        for (int c = 0; c < CPT; c++) acc[r][c] = 0.f;

    const float* Wp = W + tc * CPT;
    for (int k4 = 0; k4 < K / 4; k4++) {
        float4 a[RPT];
#pragma unroll
        for (int r = 0; r < RPT; r++)
            a[r] = *reinterpret_cast<const float4*>(&tile[rg * RPT + r][k4 * 4]);
#pragma unroll
        for (int kk = 0; kk < 4; kk++) {
            float4 w0 = *reinterpret_cast<const float4*>(Wp + (size_t)(k4 * 4 + kk) * NOUT);
            float4 w1 = *reinterpret_cast<const float4*>(Wp + (size_t)(k4 * 4 + kk) * NOUT + 4);
#pragma unroll
            for (int r = 0; r < RPT; r++) {
                float av = (&a[r].x)[kk];
                acc[r][0] += av * w0.x; acc[r][1] += av * w0.y;
                acc[r][2] += av * w0.z; acc[r][3] += av * w0.w;
                acc[r][4] += av * w1.x; acc[r][5] += av * w1.y;
                acc[r][6] += av * w1.z; acc[r][7] += av * w1.w;
            }
        }
    }

    float4 b0 = make_float4(0.f, 0.f, 0.f, 0.f), b1 = b0;
    if (BIASRELU) {
        b0 = *reinterpret_cast<const float4*>(bias + tc * CPT);
        b1 = *reinterpret_cast<const float4*>(bias + tc * CPT + 4);
    }
#pragma unroll
    for (int r = 0; r < RPT; r++) {
        int row = row0 + rg * RPT + r;
        if (row < N_NODES) {
            float4 o0, o1;
            o0.x = acc[r][0] + b0.x; o0.y = acc[r][1] + b0.y;
            o0.z = acc[r][2] + b0.z; o0.w = acc[r][3] + b0.w;
            o1.x = acc[r][4] + b1.x; o1.y = acc[r][5] + b1.y;
            o1.z = acc[r][6] + b1.z; o1.w = acc[r][7] + b1.w;
            if (BIASRELU) {
                o0.x = fmaxf(o0.x, 0.f); o0.y = fmaxf(o0.y, 0.f);
                o0.z = fmaxf(o0.z, 0.f); o0.w = fmaxf(o0.w, 0.f);
                o1.x = fmaxf(o1.x, 0.f); o1.y = fmaxf(o1.y, 0.f);
                o1.z = fmaxf(o1.z, 0.f); o1.w = fmaxf(o1.w, 0.f);
            }
            *reinterpret_cast<float4*>(out + (size_t)row * NOUT + tc * CPT)     = o0;
            *reinterpret_cast<float4*>(out + (size_t)row * NOUT + tc * CPT + 4) = o1;
        }
    }
}

// ---------------- sum pooling ----------------
__global__ void pool_kernel(const float* __restrict__ X, const int* __restrict__ gid,
                            float* __restrict__ emb) {
    int idx = blockIdx.x * 256 + threadIdx.x;   // N_NODES * 32 threads
    int n = idx >> 5;
    int c = (idx & 31) << 2;
    if (n < N_NODES) {
        int g = gid[n];
        float4 v = *reinterpret_cast<const float4*>(X + (size_t)n * 128 + c);
        float* base = emb + (size_t)g * 128 + c;
        atomicAdd(base + 0, v.x);
        atomicAdd(base + 1, v.y);
        atomicAdd(base + 2, v.z);
        atomicAdd(base + 3, v.w);
    }
}

// ---------------- batch norm (training stats, biased var) ----------------
__global__ __launch_bounds__(128) void bn_kernel(const float* __restrict__ emb,
        const float* __restrict__ gamma, const float* __restrict__ beta,
        float* __restrict__ bn) {
    int c = threadIdx.x;
    float s = 0.f;
    for (int g = 0; g < N_GRAPHS; g++) s += emb[g * 128 + c];
    float mean = s * (1.0f / N_GRAPHS);
    float v = 0.f;
    for (int g = 0; g < N_GRAPHS; g++) {
        float d = emb[g * 128 + c] - mean;
        v += d * d;
    }
    v *= (1.0f / N_GRAPHS);
    float scale = rsqrtf(v + BN_EPS) * gamma[c];
    float shift = beta[c] - mean * scale;
    for (int g = 0; g < N_GRAPHS; g++)
        bn[g * 128 + c] = emb[g * 128 + c] * scale + shift;
}

// ---------------- FC head + log_softmax ----------------
__global__ __launch_bounds__(128) void fc_kernel(const float* __restrict__ bn,
        const float* __restrict__ Wf1, const float* __restrict__ bf1,
        const float* __restrict__ Wf2, const float* __restrict__ bf2,
        float* __restrict__ out_ls) {
    __shared__ float h[H2];
    __shared__ float logits[OUT_DIM];
    int g = blockIdx.x;
    int j = threadIdx.x;
    const float* bnr = bn + g * H2;
    float acc = bf1[j];
    for (int k = 0; k < H2; k++) acc += bnr[k] * Wf1[k * H2 + j];
    h[j] = fmaxf(acc, 0.f);
    __syncthreads();
    if (j < OUT_DIM) {
        float a2 = bf2[j];
        for (int k = 0; k < H2; k++) a2 += h[k] * Wf2[k * OUT_DIM + j];
        logits[j] = a2;
    }
    __syncthreads();
    if (j < OUT_DIM) {
        float m = -1e30f;
        for (int o = 0; o < OUT_DIM; o++) m = fmaxf(m, logits[o]);
        float se = 0.f;
        for (int o = 0; o < OUT_DIM; o++) se += expf(logits[o] - m);
        out_ls[g * OUT_DIM + j] = logits[j] - m - logf(se);
    }
}

extern "C" void kernel_launch(void* const* d_in, const int* in_sizes, int n_in,
                              void* d_out, int out_size, void* d_ws, size_t ws_size,
                              hipStream_t stream) {
    const float* n_feat = (const float*)d_in[0];
    const int*   src    = (const int*)d_in[1];
    const int*   dst    = (const int*)d_in[2];
    const int*   gid    = (const int*)d_in[3];
    const float* W1     = (const float*)d_in[4];
    const float* b1     = (const float*)d_in[5];
    const float* W2     = (const float*)d_in[6];
    const float* b2     = (const float*)d_in[7];
    const float* W3     = (const float*)d_in[8];
    const float* b3     = (const float*)d_in[9];
    const float* Wf1    = (const float*)d_in[10];
    const float* bf1    = (const float*)d_in[11];
    const float* Wf2    = (const float*)d_in[12];
    const float* bf2    = (const float*)d_in[13];
    const float* gamma  = (const float*)d_in[14];
    const float* beta   = (const float*)d_in[15];
    float* out = (float*)d_out;

    char* ws = (char*)d_ws;
    size_t off = 0;
    auto alloc = [&](size_t bytes) {
        void* p = ws + off;
        off = (off + bytes + 255) & ~(size_t)255;
        return p;
    };
    float* outdeg  = (float*)alloc((size_t)N_NODES * 4);
    int*   indeg   = (int*)  alloc((size_t)N_NODES * 4);
    float* out_dis = (float*)alloc((size_t)N_NODES * 4);
    float* in_dis  = (float*)alloc((size_t)N_NODES * 4);
    int*   rowptr  = (int*)  alloc((size_t)(N_NODES + 1) * 4);
    int*   cursor  = (int*)  alloc((size_t)N_NODES * 4);
    int*   csr_src = (int*)  alloc((size_t)N_EDGES * 4);
    float* A       = (float*)alloc((size_t)N_NODES * 128 * 4);
    float* B       = (float*)alloc((size_t)N_NODES * 256 * 4);
    float* bn      = (float*)alloc((size_t)N_GRAPHS * H2 * 4);

    hipMemsetAsync(outdeg, 0, (size_t)N_NODES * 4, stream);
    hipMemsetAsync(indeg, 0, (size_t)N_NODES * 4, stream);
    hipMemsetAsync(d_out, 0, (size_t)N_GRAPHS * H2 * sizeof(float), stream);

    deg_kernel<<<(N_EDGES + 255) / 256, 256, 0, stream>>>(src, dst, outdeg, indeg);
    dis_kernel<<<(N_NODES + 255) / 256, 256, 0, stream>>>(outdeg, indeg, out_dis, in_dis);
    scan_kernel<<<1, 1024, 0, stream>>>(indeg, rowptr, cursor);
    csr_fill<<<(N_EDGES + 255) / 256, 256, 0, stream>>>(src, dst, cursor, csr_src);

    // Layer 1: A = norm-agg(n_feat) [N,128]; B = relu(A@W1 + b1) [N,256]
    pull_agg<false><<<N_NODES, 128, 0, stream>>>(n_feat, rowptr, csr_src, out_dis, in_dis, nullptr, A);
    gemm_kernel<128, 256, true><<<(N_NODES + 31) / 32, 256, 0, stream>>>(A, W1, b1, B);

    // Layer 2 (GEMM first — aggregation is linear): A = B@W2 [N,128]; B = relu(agg(A) + b2) [N,128]
    gemm_kernel<256, 128, false><<<(N_NODES + 31) / 32, 256, 0, stream>>>(B, W2, nullptr, A);
    pull_agg<true><<<N_NODES, 128, 0, stream>>>(A, rowptr, csr_src, out_dis, in_dis, b2, B);

    // Layer 3: A = norm-agg(B) [N,128]; B = relu(A@W3 + b3) [N,128]
    pull_agg<false><<<N_NODES, 128, 0, stream>>>(B, rowptr, csr_src, out_dis, in_dis, nullptr, A);
    gemm_kernel<128, 128, true><<<(N_NODES + 31) / 32, 256, 0, stream>>>(A, W3, b3, B);

    // Readout
    pool_kernel<<<(N_NODES * 32) / 256, 256, 0, stream>>>(B, gid, out);
    bn_kernel<<<1, 128, 0, stream>>>(out, gamma, beta, bn);
    fc_kernel<<<N_GRAPHS, 128, 0, stream>>>(bn, Wf1, bf1, Wf2, bf2, out + (size_t)N_GRAPHS * H2);
}

// Round 2
// 701.534 us; speedup vs baseline: 1.3288x; 1.3288x over previous
//
#include <hip/hip_runtime.h>

#define N_NODES 50000
#define N_EDGES 800000
#define N_GRAPHS 128
#define IN_DIM 128
#define HID 256
#define H2 128
#define OUT_DIM 10
#define BN_EPS 1e-5f

// ---------------- degree + normalization ----------------
__global__ void deg_kernel(const int* __restrict__ src, const int* __restrict__ dst,
                           int* __restrict__ outdeg, int* __restrict__ indeg) {
    int e = blockIdx.x * 256 + threadIdx.x;
    if (e < N_EDGES) {
        atomicAdd(&outdeg[src[e]], 1);
        atomicAdd(&indeg[dst[e]], 1);
    }
}

__global__ void dis_kernel(const int* __restrict__ outdeg, const int* __restrict__ indeg,
                           float* __restrict__ out_dis, float* __restrict__ in_dis) {
    int i = blockIdx.x * 256 + threadIdx.x;
    if (i < N_NODES) {
        out_dis[i] = rsqrtf(fmaxf((float)outdeg[i], 1.0f));
        in_dis[i]  = rsqrtf(fmaxf((float)indeg[i], 1.0f));
    }
}

// ---------------- CSR build: scan + fill ----------------
__global__ __launch_bounds__(1024) void scan_kernel(const int* __restrict__ indeg,
                                                    int* __restrict__ rowptr,
                                                    int* __restrict__ cursor) {
    __shared__ int sums[1024];
    int t = threadIdx.x;
    const int per = (N_NODES + 1023) / 1024;   // 49
    int beg = t * per;
    int end = min(beg + per, N_NODES);
    int s = 0;
    for (int i = beg; i < end; i++) s += indeg[i];
    sums[t] = s;
    __syncthreads();
    for (int off = 1; off < 1024; off <<= 1) {
        int u = (t >= off) ? sums[t - off] : 0;
        __syncthreads();
        sums[t] += u;
        __syncthreads();
    }
    int run = (t == 0) ? 0 : sums[t - 1];
    for (int i = beg; i < end; i++) {
        rowptr[i] = run;
        cursor[i] = run;
        run += indeg[i];
    }
    if (end == N_NODES) rowptr[N_NODES] = sums[1023];
}

__global__ void csr_fill(const int* __restrict__ src, const int* __restrict__ dst,
                         int* __restrict__ cursor, int* __restrict__ csr_src) {
    int e = blockIdx.x * 256 + threadIdx.x;
    if (e < N_EDGES) {
        int pos = atomicAdd(&cursor[dst[e]], 1);
        csr_src[pos] = src[e];
    }
}

// ---------------- pull aggregation (D = 128, one wave per node, float2/lane) ----------
// MODE 0: out[n] = acc * in_dis[n]                      (input pre-scaled by out_dis)
// MODE 1: out[n] = relu(acc*in_dis[n] + bias) * out_dis[n]   (input pre-scaled)
// MODE 2: acc += X[s]*out_dis[s];  out[n] = acc * in_dis[n]  (src-scaled gather, layer 1)
template<int MODE>
__global__ __launch_bounds__(256) void pull_agg(const float* __restrict__ X,
        const int* __restrict__ rowptr, const int* __restrict__ csr_src,
        const float* __restrict__ out_dis, const float* __restrict__ in_dis,
        const float* __restrict__ bias, float* __restrict__ out) {
    int wave = threadIdx.x >> 6;
    int lane = threadIdx.x & 63;
    int n = blockIdx.x * 4 + wave;
    if (n >= N_NODES) return;
    int beg = rowptr[n], end = rowptr[n + 1];
    const int c2 = lane * 2;
    float ax = 0.f, ay = 0.f;
    int e = beg;
    for (; e + 4 <= end; e += 4) {
        int s0 = csr_src[e + 0], s1 = csr_src[e + 1];
        int s2 = csr_src[e + 2], s3 = csr_src[e + 3];
        float2 x0 = *reinterpret_cast<const float2*>(X + (size_t)s0 * 128 + c2);
        float2 x1 = *reinterpret_cast<const float2*>(X + (size_t)s1 * 128 + c2);
        float2 x2 = *reinterpret_cast<const float2*>(X + (size_t)s2 * 128 + c2);
        float2 x3 = *reinterpret_cast<const float2*>(X + (size_t)s3 * 128 + c2);
        if (MODE == 2) {
            float d0 = out_dis[s0], d1 = out_dis[s1], d2 = out_dis[s2], d3 = out_dis[s3];
            ax += x0.x * d0 + x1.x * d1 + x2.x * d2 + x3.x * d3;
            ay += x0.y * d0 + x1.y * d1 + x2.y * d2 + x3.y * d3;
        } else {
            ax += x0.x + x1.x + x2.x + x3.x;
            ay += x0.y + x1.y + x2.y + x3.y;
        }
    }
    for (; e < end; e++) {
        int s = csr_src[e];
        float2 x = *reinterpret_cast<const float2*>(X + (size_t)s * 128 + c2);
        if (MODE == 2) {
            float d = out_dis[s];
            ax += x.x * d; ay += x.y * d;
        } else {
            ax += x.x; ay += x.y;
        }
    }
    float id = in_dis[n];
    float vx = ax * id, vy = ay * id;
    if (MODE == 1) {
        float od = out_dis[n];
        vx = fmaxf(vx + bias[c2], 0.f) * od;
        vy = fmaxf(vy + bias[c2 + 1], 0.f) * od;
    }
    *reinterpret_cast<float2*>(out + (size_t)n * 128 + c2) = make_float2(vx, vy);
}

// ---------------- register-tiled f32 GEMM: out[M,NOUT] = A[M,K] @ W[K,NOUT] ----------------
// EPI 0: none   EPI 1: bias + relu   EPI 2: row-scale by od[row]
template<int K, int NOUT, int EPI>
__global__ __launch_bounds__(256) void gemm_kernel(const float* __restrict__ A,
        const float* __restrict__ W, const float* __restrict__ aux,
        float* __restrict__ out) {
    constexpr int BM  = 32;
    constexpr int CPT = 8;
    constexpr int TC  = NOUT / CPT;
    constexpr int RG  = 256 / TC;
    constexpr int RPT = BM / RG;
    __shared__ float tile[BM][K];

    int row0 = blockIdx.x * BM;
    for (int i = threadIdx.x; i < BM * K; i += 256) {
        int r = i / K, k = i - r * K;
        int row = row0 + r;
        tile[r][k] = (row < N_NODES) ? A[(size_t)row * K + k] : 0.f;
    }
    __syncthreads();

    int tc = threadIdx.x % TC;
    int rg = threadIdx.x / TC;
    float acc[RPT][CPT];
#pragma unroll
    for (int r = 0; r < RPT; r++)
#pragma unroll
        for (int c = 0; c < CPT; c++) acc[r][c] = 0.f;

    const float* Wp = W + tc * CPT;
    for (int k4 = 0; k4 < K / 4; k4++) {
        float4 a[RPT];
#pragma unroll
        for (int r = 0; r < RPT; r++)
            a[r] = *reinterpret_cast<const float4*>(&tile[rg * RPT + r][k4 * 4]);
#pragma unroll
        for (int kk = 0; kk < 4; kk++) {
            float4 w0 = *reinterpret_cast<const float4*>(Wp + (size_t)(k4 * 4 + kk) * NOUT);
            float4 w1 = *reinterpret_cast<const float4*>(Wp + (size_t)(k4 * 4 + kk) * NOUT + 4);
#pragma unroll
            for (int r = 0; r < RPT; r++) {
                float av = (&a[r].x)[kk];
                acc[r][0] += av * w0.x; acc[r][1] += av * w0.y;
                acc[r][2] += av * w0.z; acc[r][3] += av * w0.w;
                acc[r][4] += av * w1.x; acc[r][5] += av * w1.y;
                acc[r][6] += av * w1.z; acc[r][7] += av * w1.w;
            }
        }
    }

    float4 b0 = make_float4(0.f, 0.f, 0.f, 0.f), b1 = b0;
    if (EPI == 1) {
        b0 = *reinterpret_cast<const float4*>(aux + tc * CPT);
        b1 = *reinterpret_cast<const float4*>(aux + tc * CPT + 4);
    }
#pragma unroll
    for (int r = 0; r < RPT; r++) {
        int row = row0 + rg * RPT + r;
        if (row < N_NODES) {
            float s = (EPI == 2) ? aux[row] : 1.0f;
            float4 o0, o1;
            o0.x = acc[r][0] + b0.x; o0.y = acc[r][1] + b0.y;
            o0.z = acc[r][2] + b0.z; o0.w = acc[r][3] + b0.w;
            o1.x = acc[r][4] + b1.x; o1.y = acc[r][5] + b1.y;
            o1.z = acc[r][6] + b1.z; o1.w = acc[r][7] + b1.w;
            if (EPI == 1) {
                o0.x = fmaxf(o0.x, 0.f); o0.y = fmaxf(o0.y, 0.f);
                o0.z = fmaxf(o0.z, 0.f); o0.w = fmaxf(o0.w, 0.f);
                o1.x = fmaxf(o1.x, 0.f); o1.y = fmaxf(o1.y, 0.f);
                o1.z = fmaxf(o1.z, 0.f); o1.w = fmaxf(o1.w, 0.f);
            } else if (EPI == 2) {
                o0.x *= s; o0.y *= s; o0.z *= s; o0.w *= s;
                o1.x *= s; o1.y *= s; o1.z *= s; o1.w *= s;
            }
            *reinterpret_cast<float4*>(out + (size_t)row * NOUT + tc * CPT)     = o0;
            *reinterpret_cast<float4*>(out + (size_t)row * NOUT + tc * CPT + 4) = o1;
        }
    }
}

// ---------------- graph segment boundaries (graph_ids is sorted) ----------------
__global__ void bounds_kernel(const int* __restrict__ gid, int* __restrict__ gstart) {
    int n = blockIdx.x * 256 + threadIdx.x;
    if (n >= N_NODES) return;
    int g = gid[n];
    int gp = (n == 0) ? -1 : gid[n - 1];
    for (int k = gp + 1; k <= g; k++) gstart[k] = n;
    if (n == N_NODES - 1)
        for (int k = g + 1; k <= N_GRAPHS; k++) gstart[k] = N_NODES;
}

// ---------------- sum pooling over contiguous segments (no atomics) ----------------
__global__ __launch_bounds__(512) void seg_pool(const float* __restrict__ X,
        const int* __restrict__ gstart, float* __restrict__ emb) {
    int g = blockIdx.x;
    int c = threadIdx.x & 127;
    int stripe = threadIdx.x >> 7;   // 0..3
    int beg = gstart[g], end = gstart[g + 1];
    float acc = 0.f;
    for (int r = beg + stripe; r < end; r += 4)
        acc += X[(size_t)r * 128 + c];
    __shared__ float buf[4][128];
    buf[stripe][c] = acc;
    __syncthreads();
    if (stripe == 0)
        emb[g * 128 + c] = buf[0][c] + buf[1][c] + buf[2][c] + buf[3][c];
}

// ---------------- batch norm (training stats, biased var) ----------------
__global__ __launch_bounds__(128) void bn_kernel(const float* __restrict__ emb,
        const float* __restrict__ gamma, const float* __restrict__ beta,
        float* __restrict__ bn) {
    int c = threadIdx.x;
    float s = 0.f;
    for (int g = 0; g < N_GRAPHS; g++) s += emb[g * 128 + c];
    float mean = s * (1.0f / N_GRAPHS);
    float v = 0.f;
    for (int g = 0; g < N_GRAPHS; g++) {
        float d = emb[g * 128 + c] - mean;
        v += d * d;
    }
    v *= (1.0f / N_GRAPHS);
    float scale = rsqrtf(v + BN_EPS) * gamma[c];
    float shift = beta[c] - mean * scale;
    for (int g = 0; g < N_GRAPHS; g++)
        bn[g * 128 + c] = emb[g * 128 + c] * scale + shift;
}

// ---------------- FC head + log_softmax ----------------
__global__ __launch_bounds__(128) void fc_kernel(const float* __restrict__ bn,
        const float* __restrict__ Wf1, const float* __restrict__ bf1,
        const float* __restrict__ Wf2, const float* __restrict__ bf2,
        float* __restrict__ out_ls) {
    __shared__ float h[H2];
    __shared__ float logits[OUT_DIM];
    int g = blockIdx.x;
    int j = threadIdx.x;
    const float* bnr = bn + g * H2;
    float acc = bf1[j];
    for (int k = 0; k < H2; k++) acc += bnr[k] * Wf1[k * H2 + j];
    h[j] = fmaxf(acc, 0.f);
    __syncthreads();
    if (j < OUT_DIM) {
        float a2 = bf2[j];
        for (int k = 0; k < H2; k++) a2 += h[k] * Wf2[k * OUT_DIM + j];
        logits[j] = a2;
    }
    __syncthreads();
    if (j < OUT_DIM) {
        float m = -1e30f;
        for (int o = 0; o < OUT_DIM; o++) m = fmaxf(m, logits[o]);
        float se = 0.f;
        for (int o = 0; o < OUT_DIM; o++) se += expf(logits[o] - m);
        out_ls[g * OUT_DIM + j] = logits[j] - m - logf(se);
    }
}

extern "C" void kernel_launch(void* const* d_in, const int* in_sizes, int n_in,
                              void* d_out, int out_size, void* d_ws, size_t ws_size,
                              hipStream_t stream) {
    const float* n_feat = (const float*)d_in[0];
    const int*   src    = (const int*)d_in[1];
    const int*   dst    = (const int*)d_in[2];
    const int*   gid    = (const int*)d_in[3];
    const float* W1     = (const float*)d_in[4];
    const float* b1     = (const float*)d_in[5];
    const float* W2     = (const float*)d_in[6];
    const float* b2     = (const float*)d_in[7];
    const float* W3     = (const float*)d_in[8];
    const float* b3     = (const float*)d_in[9];
    const float* Wf1    = (const float*)d_in[10];
    const float* bf1    = (const float*)d_in[11];
    const float* Wf2    = (const float*)d_in[12];
    const float* bf2    = (const float*)d_in[13];
    const float* gamma  = (const float*)d_in[14];
    const float* beta   = (const float*)d_in[15];
    float* out = (float*)d_out;

    char* ws = (char*)d_ws;
    size_t off = 0;
    auto alloc = [&](size_t bytes) {
        void* p = ws + off;
        off = (off + bytes + 255) & ~(size_t)255;
        return p;
    };
    int*   outdeg  = (int*)  alloc((size_t)N_NODES * 4);
    int*   indeg   = (int*)  alloc((size_t)N_NODES * 4);
    float* out_dis = (float*)alloc((size_t)N_NODES * 4);
    float* in_dis  = (float*)alloc((size_t)N_NODES * 4);
    int*   rowptr  = (int*)  alloc((size_t)(N_NODES + 1) * 4);
    int*   cursor  = (int*)  alloc((size_t)N_NODES * 4);
    int*   gstart  = (int*)  alloc((size_t)(N_GRAPHS + 1) * 4);
    int*   csr_src = (int*)  alloc((size_t)N_EDGES * 4);
    float* A       = (float*)alloc((size_t)N_NODES * 128 * 4);
    float* B       = (float*)alloc((size_t)N_NODES * 256 * 4);   // also reused as [N,128]
    float* bn      = (float*)alloc((size_t)N_GRAPHS * H2 * 4);

    hipMemsetAsync(outdeg, 0, (size_t)N_NODES * 4, stream);
    hipMemsetAsync(indeg, 0, (size_t)N_NODES * 4, stream);

    deg_kernel<<<(N_EDGES + 255) / 256, 256, 0, stream>>>(src, dst, outdeg, indeg);
    dis_kernel<<<(N_NODES + 255) / 256, 256, 0, stream>>>(outdeg, indeg, out_dis, in_dis);
    scan_kernel<<<1, 1024, 0, stream>>>(indeg, rowptr, cursor);
    csr_fill<<<(N_EDGES + 255) / 256, 256, 0, stream>>>(src, dst, cursor, csr_src);
    bounds_kernel<<<(N_NODES + 255) / 256, 256, 0, stream>>>(gid, gstart);

    const int AGG_GRID = (N_NODES + 3) / 4;

    // Layer 1: A = agg(n_feat · od) · id ; B = relu(A@W1 + b1)   [N,256]
    pull_agg<2><<<AGG_GRID, 256, 0, stream>>>(n_feat, rowptr, csr_src, out_dis, in_dis, nullptr, A);
    gemm_kernel<128, 256, 1><<<(N_NODES + 31) / 32, 256, 0, stream>>>(A, W1, b1, B);

    // Layer 2: A = (x1@W2) · od ; B[:,:128] = relu(agg(A)·id + b2) · od
    gemm_kernel<256, 128, 2><<<(N_NODES + 31) / 32, 256, 0, stream>>>(B, W2, out_dis, A);
    pull_agg<1><<<AGG_GRID, 256, 0, stream>>>(A, rowptr, csr_src, out_dis, in_dis, b2, B);

    // Layer 3: A = agg(B) · id ; B = relu(A@W3 + b3)
    pull_agg<0><<<AGG_GRID, 256, 0, stream>>>(B, rowptr, csr_src, out_dis, in_dis, nullptr, A);
    gemm_kernel<128, 128, 1><<<(N_NODES + 31) / 32, 256, 0, stream>>>(A, W3, b3, B);

    // Readout: segmented sum pooling (graph_ids sorted), BN, FC head
    seg_pool<<<N_GRAPHS, 512, 0, stream>>>(B, gstart, out);
    bn_kernel<<<1, 128, 0, stream>>>(out, gamma, beta, bn);
    fc_kernel<<<N_GRAPHS, 128, 0, stream>>>(bn, Wf1, bf1, Wf2, bf2, out + (size_t)N_GRAPHS * H2);
}

// Round 3
// 528.016 us; speedup vs baseline: 1.7655x; 1.3286x over previous
//
#include <hip/hip_runtime.h>

#define N_NODES 50000
#define N_EDGES 800000
#define N_GRAPHS 128
#define IN_DIM 128
#define HID 256
#define H2 128
#define OUT_DIM 10
#define BN_EPS 1e-5f

typedef __attribute__((ext_vector_type(8))) short short8_t;   // 8 bf16 (4 VGPRs)
typedef __attribute__((ext_vector_type(4))) float f32x4;

__device__ __forceinline__ unsigned short f2bf(float f) {
    union { float f; unsigned u; } x; x.f = f;
    unsigned r = x.u + 0x7fffu + ((x.u >> 16) & 1u);   // round-to-nearest-even
    return (unsigned short)(r >> 16);
}
__device__ __forceinline__ float bf2f(unsigned short h) {
    union { unsigned u; float f; } x; x.u = ((unsigned)h) << 16;
    return x.f;
}

// ---------------- degree + normalization ----------------
__global__ void deg_kernel(const int* __restrict__ src, const int* __restrict__ dst,
                           int* __restrict__ outdeg, int* __restrict__ indeg) {
    int e = blockIdx.x * 256 + threadIdx.x;
    if (e < N_EDGES) {
        atomicAdd(&outdeg[src[e]], 1);
        atomicAdd(&indeg[dst[e]], 1);
    }
}

__global__ void dis_kernel(const int* __restrict__ outdeg, const int* __restrict__ indeg,
                           float* __restrict__ out_dis, float* __restrict__ in_dis) {
    int i = blockIdx.x * 256 + threadIdx.x;
    if (i < N_NODES) {
        out_dis[i] = rsqrtf(fmaxf((float)outdeg[i], 1.0f));
        in_dis[i]  = rsqrtf(fmaxf((float)indeg[i], 1.0f));
    }
}

// ---------------- CSR build: scan + fill ----------------
__global__ __launch_bounds__(1024) void scan_kernel(const int* __restrict__ indeg,
                                                    int* __restrict__ rowptr,
                                                    int* __restrict__ cursor) {
    __shared__ int sums[1024];
    int t = threadIdx.x;
    const int per = (N_NODES + 1023) / 1024;
    int beg = t * per;
    int end = min(beg + per, N_NODES);
    int s = 0;
    for (int i = beg; i < end; i++) s += indeg[i];
    sums[t] = s;
    __syncthreads();
    for (int off = 1; off < 1024; off <<= 1) {
        int u = (t >= off) ? sums[t - off] : 0;
        __syncthreads();
        sums[t] += u;
        __syncthreads();
    }
    int run = (t == 0) ? 0 : sums[t - 1];
    for (int i = beg; i < end; i++) {
        rowptr[i] = run;
        cursor[i] = run;
        run += indeg[i];
    }
    if (end == N_NODES) rowptr[N_NODES] = sums[1023];
}

__global__ void csr_fill(const int* __restrict__ src, const int* __restrict__ dst,
                         int* __restrict__ cursor, int* __restrict__ csr_src) {
    int e = blockIdx.x * 256 + threadIdx.x;
    if (e < N_EDGES) {
        int pos = atomicAdd(&cursor[dst[e]], 1);
        csr_src[pos] = src[e];
    }
}

// ---------------- weight convert + transpose: W[K][NOUT] f32 -> WT[NOUT][K] bf16 ----------
__global__ void convw_kernel(const float* __restrict__ W, unsigned short* __restrict__ WT,
                             int K, int NOUT) {
    int i = blockIdx.x * 256 + threadIdx.x;
    if (i < K * NOUT) {
        int k = i / NOUT, n = i - k * NOUT;
        WT[(size_t)n * K + k] = f2bf(W[i]);
    }
}

// ---------------- pull aggregation (D=128, one wave/node, 2 cols/lane) ----------
// MODE 2: in f32, acc += X[s]*out_dis[s]; out = bf16(acc*id)            (layer 1)
// MODE 0: in bf16 (pre-scaled), out = bf16(acc*id)                      (layer 3)
// MODE 1: in bf16 (pre-scaled), out = bf16(relu(acc*id + bias)*od)      (layer 2)
template<int MODE>
__global__ __launch_bounds__(256) void pull_agg(const void* __restrict__ Xv,
        const int* __restrict__ rowptr, const int* __restrict__ csr_src,
        const float* __restrict__ out_dis, const float* __restrict__ in_dis,
        const float* __restrict__ bias, unsigned int* __restrict__ out) {
    int wave = threadIdx.x >> 6;
    int lane = threadIdx.x & 63;
    int n = blockIdx.x * 4 + wave;
    if (n >= N_NODES) return;
    int beg = rowptr[n], end = rowptr[n + 1];
    const int c2 = lane * 2;
    float ax = 0.f, ay = 0.f;
    int e = beg;
    if (MODE == 2) {
        const float* X = (const float*)Xv;
        for (; e + 4 <= end; e += 4) {
            int s0 = csr_src[e], s1 = csr_src[e + 1], s2 = csr_src[e + 2], s3 = csr_src[e + 3];
            float2 x0 = *reinterpret_cast<const float2*>(X + (size_t)s0 * 128 + c2);
            float2 x1 = *reinterpret_cast<const float2*>(X + (size_t)s1 * 128 + c2);
            float2 x2 = *reinterpret_cast<const float2*>(X + (size_t)s2 * 128 + c2);
            float2 x3 = *reinterpret_cast<const float2*>(X + (size_t)s3 * 128 + c2);
            float d0 = out_dis[s0], d1 = out_dis[s1], d2 = out_dis[s2], d3 = out_dis[s3];
            ax += x0.x * d0 + x1.x * d1 + x2.x * d2 + x3.x * d3;
            ay += x0.y * d0 + x1.y * d1 + x2.y * d2 + x3.y * d3;
        }
        for (; e < end; e++) {
            int s = csr_src[e];
            float2 x = *reinterpret_cast<const float2*>(X + (size_t)s * 128 + c2);
            float d = out_dis[s];
            ax += x.x * d; ay += x.y * d;
        }
    } else {
        const unsigned int* X = (const unsigned int*)Xv;
        for (; e + 4 <= end; e += 4) {
            int s0 = csr_src[e], s1 = csr_src[e + 1], s2 = csr_src[e + 2], s3 = csr_src[e + 3];
            unsigned u0 = X[(size_t)s0 * 64 + lane];
            unsigned u1 = X[(size_t)s1 * 64 + lane];
            unsigned u2 = X[(size_t)s2 * 64 + lane];
            unsigned u3 = X[(size_t)s3 * 64 + lane];
            ax += bf2f((unsigned short)(u0 & 0xffff)) + bf2f((unsigned short)(u1 & 0xffff))
                + bf2f((unsigned short)(u2 & 0xffff)) + bf2f((unsigned short)(u3 & 0xffff));
            ay += bf2f((unsigned short)(u0 >> 16)) + bf2f((unsigned short)(u1 >> 16))
                + bf2f((unsigned short)(u2 >> 16)) + bf2f((unsigned short)(u3 >> 16));
        }
        for (; e < end; e++) {
            int s = csr_src[e];
            unsigned u = X[(size_t)s * 64 + lane];
            ax += bf2f((unsigned short)(u & 0xffff));
            ay += bf2f((unsigned short)(u >> 16));
        }
    }
    float id = in_dis[n];
    float vx = ax * id, vy = ay * id;
    if (MODE == 1) {
        float od = out_dis[n];
        vx = fmaxf(vx + bias[c2], 0.f) * od;
        vy = fmaxf(vy + bias[c2 + 1], 0.f) * od;
    }
    out[(size_t)n * 64 + lane] = (unsigned)f2bf(vx) | ((unsigned)f2bf(vy) << 16);
}

// ---------------- MFMA bf16 GEMM: out[M,NOUT] = A[M,K] @ W[K,NOUT] ----------------
// A: bf16 [M,K] row-major.  WT: bf16 [NOUT,K] row-major (= W^T).
// EPI 1: bias+relu (aux=bias[NOUT])   EPI 2: row-scale (aux=od[M])
// Block: 256 threads = 4 waves; BM = 64 (16 rows per wave); each wave covers all NOUT.
template<int K, int NOUT, int EPI>
__global__ __launch_bounds__(256) void mfma_gemm(const unsigned short* __restrict__ A,
        const unsigned short* __restrict__ WT, const float* __restrict__ aux,
        unsigned short* __restrict__ out) {
    constexpr int NB = NOUT / 16;
    int wave = threadIdx.x >> 6;
    int lane = threadIdx.x & 63;
    int row0 = blockIdx.x * 64 + wave * 16;
    int arow = row0 + (lane & 15);
    int kgrp = (lane >> 4) * 8;

    f32x4 acc[NB];
#pragma unroll
    for (int n = 0; n < NB; n++) acc[n] = f32x4{0.f, 0.f, 0.f, 0.f};

    const unsigned short* wp0 = WT + (size_t)(lane & 15) * K + kgrp;
    for (int kk = 0; kk < K; kk += 32) {
        short8_t a;
        if (arow < N_NODES)
            a = *reinterpret_cast<const short8_t*>(A + (size_t)arow * K + kk + kgrp);
        else
            a = short8_t{0, 0, 0, 0, 0, 0, 0, 0};
        const unsigned short* wp = wp0 + kk;
#pragma unroll
        for (int n = 0; n < NB; n++) {
            short8_t b = *reinterpret_cast<const short8_t*>(wp + (size_t)n * 16 * K);
            acc[n] = __builtin_amdgcn_mfma_f32_16x16x32_bf16(a, b, acc[n], 0, 0, 0);
        }
    }

    // C/D layout: col = lane&15, row = (lane>>4)*4 + reg
    int col0 = lane & 15;
    int rbase = row0 + ((lane >> 4) << 2);
    float rs[4];
    if (EPI == 2) {
#pragma unroll
        for (int j = 0; j < 4; j++)
            rs[j] = (rbase + j < N_NODES) ? aux[rbase + j] : 0.f;
    }
#pragma unroll
    for (int n = 0; n < NB; n++) {
        int col = n * 16 + col0;
        float bv = (EPI == 1) ? aux[col] : 0.f;
#pragma unroll
        for (int j = 0; j < 4; j++) {
            int row = rbase + j;
            if (row < N_NODES) {
                float v = acc[n][j];
                if (EPI == 1) v = fmaxf(v + bv, 0.f);
                if (EPI == 2) v = v * rs[j];
                out[(size_t)row * NOUT + col] = f2bf(v);
            }
        }
    }
}

// ---------------- graph segment boundaries (graph_ids is sorted) ----------------
__global__ void bounds_kernel(const int* __restrict__ gid, int* __restrict__ gstart) {
    int n = blockIdx.x * 256 + threadIdx.x;
    if (n >= N_NODES) return;
    int g = gid[n];
    int gp = (n == 0) ? -1 : gid[n - 1];
    for (int k = gp + 1; k <= g; k++) gstart[k] = n;
    if (n == N_NODES - 1)
        for (int k = g + 1; k <= N_GRAPHS; k++) gstart[k] = N_NODES;
}

// ---------------- sum pooling over contiguous segments (bf16 in, f32 out) ----------
__global__ __launch_bounds__(512) void seg_pool(const unsigned short* __restrict__ X,
        const int* __restrict__ gstart, float* __restrict__ emb) {
    int g = blockIdx.x;
    int c = threadIdx.x & 127;
    int stripe = threadIdx.x >> 7;
    int beg = gstart[g], end = gstart[g + 1];
    float acc = 0.f;
    for (int r = beg + stripe; r < end; r += 4)
        acc += bf2f(X[(size_t)r * 128 + c]);
    __shared__ float buf[4][128];
    buf[stripe][c] = acc;
    __syncthreads();
    if (stripe == 0)
        emb[g * 128 + c] = buf[0][c] + buf[1][c] + buf[2][c] + buf[3][c];
}

// ---------------- batch norm (training stats, biased var) ----------------
__global__ __launch_bounds__(128) void bn_kernel(const float* __restrict__ emb,
        const float* __restrict__ gamma, const float* __restrict__ beta,
        float* __restrict__ bn) {
    int c = threadIdx.x;
    float s = 0.f;
    for (int g = 0; g < N_GRAPHS; g++) s += emb[g * 128 + c];
    float mean = s * (1.0f / N_GRAPHS);
    float v = 0.f;
    for (int g = 0; g < N_GRAPHS; g++) {
        float d = emb[g * 128 + c] - mean;
        v += d * d;
    }
    v *= (1.0f / N_GRAPHS);
    float scale = rsqrtf(v + BN_EPS) * gamma[c];
    float shift = beta[c] - mean * scale;
    for (int g = 0; g < N_GRAPHS; g++)
        bn[g * 128 + c] = emb[g * 128 + c] * scale + shift;
}

// ---------------- FC head + log_softmax ----------------
__global__ __launch_bounds__(128) void fc_kernel(const float* __restrict__ bn,
        const float* __restrict__ Wf1, const float* __restrict__ bf1,
        const float* __restrict__ Wf2, const float* __restrict__ bf2,
        float* __restrict__ out_ls) {
    __shared__ float h[H2];
    __shared__ float logits[OUT_DIM];
    int g = blockIdx.x;
    int j = threadIdx.x;
    const float* bnr = bn + g * H2;
    float acc = bf1[j];
    for (int k = 0; k < H2; k++) acc += bnr[k] * Wf1[k * H2 + j];
    h[j] = fmaxf(acc, 0.f);
    __syncthreads();
    if (j < OUT_DIM) {
        float a2 = bf2[j];
        for (int k = 0; k < H2; k++) a2 += h[k] * Wf2[k * OUT_DIM + j];
        logits[j] = a2;
    }
    __syncthreads();
    if (j < OUT_DIM) {
        float m = -1e30f;
        for (int o = 0; o < OUT_DIM; o++) m = fmaxf(m, logits[o]);
        float se = 0.f;
        for (int o = 0; o < OUT_DIM; o++) se += expf(logits[o] - m);
        out_ls[g * OUT_DIM + j] = logits[j] - m - logf(se);
    }
}

extern "C" void kernel_launch(void* const* d_in, const int* in_sizes, int n_in,
                              void* d_out, int out_size, void* d_ws, size_t ws_size,
                              hipStream_t stream) {
    const float* n_feat = (const float*)d_in[0];
    const int*   src    = (const int*)d_in[1];
    const int*   dst    = (const int*)d_in[2];
    const int*   gid    = (const int*)d_in[3];
    const float* W1     = (const float*)d_in[4];
    const float* b1     = (const float*)d_in[5];
    const float* W2     = (const float*)d_in[6];
    const float* b2     = (const float*)d_in[7];
    const float* W3     = (const float*)d_in[8];
    const float* b3     = (const float*)d_in[9];
    const float* Wf1    = (const float*)d_in[10];
    const float* bf1    = (const float*)d_in[11];
    const float* Wf2    = (const float*)d_in[12];
    const float* bf2    = (const float*)d_in[13];
    const float* gamma  = (const float*)d_in[14];
    const float* beta   = (const float*)d_in[15];
    float* out = (float*)d_out;

    char* ws = (char*)d_ws;
    size_t off = 0;
    auto alloc = [&](size_t bytes) {
        void* p = ws + off;
        off = (off + bytes + 255) & ~(size_t)255;
        return p;
    };
    int*   outdeg  = (int*)  alloc((size_t)N_NODES * 4);
    int*   indeg   = (int*)  alloc((size_t)N_NODES * 4);
    float* out_dis = (float*)alloc((size_t)N_NODES * 4);
    float* in_dis  = (float*)alloc((size_t)N_NODES * 4);
    int*   rowptr  = (int*)  alloc((size_t)(N_NODES + 1) * 4);
    int*   cursor  = (int*)  alloc((size_t)N_NODES * 4);
    int*   gstart  = (int*)  alloc((size_t)(N_GRAPHS + 1) * 4);
    int*   csr_src = (int*)  alloc((size_t)N_EDGES * 4);
    unsigned short* A   = (unsigned short*)alloc((size_t)N_NODES * 256 * 2);
    unsigned short* B   = (unsigned short*)alloc((size_t)N_NODES * 256 * 2);
    unsigned short* W1T = (unsigned short*)alloc((size_t)IN_DIM * HID * 2);
    unsigned short* W2T = (unsigned short*)alloc((size_t)HID * H2 * 2);
    unsigned short* W3T = (unsigned short*)alloc((size_t)H2 * H2 * 2);
    float* bn = (float*)alloc((size_t)N_GRAPHS * H2 * 4);

    hipMemsetAsync(outdeg, 0, (size_t)N_NODES * 4, stream);
    hipMemsetAsync(indeg, 0, (size_t)N_NODES * 4, stream);

    deg_kernel<<<(N_EDGES + 255) / 256, 256, 0, stream>>>(src, dst, outdeg, indeg);
    dis_kernel<<<(N_NODES + 255) / 256, 256, 0, stream>>>(outdeg, indeg, out_dis, in_dis);
    scan_kernel<<<1, 1024, 0, stream>>>(indeg, rowptr, cursor);
    csr_fill<<<(N_EDGES + 255) / 256, 256, 0, stream>>>(src, dst, cursor, csr_src);
    bounds_kernel<<<(N_NODES + 255) / 256, 256, 0, stream>>>(gid, gstart);
    convw_kernel<<<(IN_DIM * HID + 255) / 256, 256, 0, stream>>>(W1, W1T, IN_DIM, HID);
    convw_kernel<<<(HID * H2 + 255) / 256, 256, 0, stream>>>(W2, W2T, HID, H2);
    convw_kernel<<<(H2 * H2 + 255) / 256, 256, 0, stream>>>(W3, W3T, H2, H2);

    const int AGG_GRID = (N_NODES + 3) / 4;
    const int GEMM_GRID = (N_NODES + 63) / 64;

    // Layer 1: A = bf16(agg(n_feat·od)·id); B = bf16(relu(A@W1 + b1))  [N,256]
    pull_agg<2><<<AGG_GRID, 256, 0, stream>>>(n_feat, rowptr, csr_src, out_dis, in_dis,
                                              nullptr, (unsigned int*)A);
    mfma_gemm<128, 256, 1><<<GEMM_GRID, 256, 0, stream>>>(A, W1T, b1, B);

    // Layer 2: A = bf16((x1@W2)·od); B = bf16(relu(agg(A)·id + b2)·od)
    mfma_gemm<256, 128, 2><<<GEMM_GRID, 256, 0, stream>>>(B, W2T, out_dis, A);
    pull_agg<1><<<AGG_GRID, 256, 0, stream>>>(A, rowptr, csr_src, out_dis, in_dis,
                                              b2, (unsigned int*)B);

    // Layer 3: A = bf16(agg(B)·id); B = bf16(relu(A@W3 + b3))
    pull_agg<0><<<AGG_GRID, 256, 0, stream>>>(B, rowptr, csr_src, out_dis, in_dis,
                                              nullptr, (unsigned int*)A);
    mfma_gemm<128, 128, 1><<<GEMM_GRID, 256, 0, stream>>>(A, W3T, b3, B);

    // Readout
    seg_pool<<<N_GRAPHS, 512, 0, stream>>>(B, gstart, out);
    bn_kernel<<<1, 128, 0, stream>>>(out, gamma, beta, bn);
    fc_kernel<<<N_GRAPHS, 128, 0, stream>>>(bn, Wf1, bf1, Wf2, bf2, out + (size_t)N_GRAPHS * H2);
}

// Round 4
// 410.288 us; speedup vs baseline: 2.2721x; 1.2869x over previous
//
#include <hip/hip_runtime.h>

#define N_NODES 50000
#define N_EDGES 800000
#define N_GRAPHS 128
#define IN_DIM 128
#define HID 256
#define H2 128
#define OUT_DIM 10
#define BN_EPS 1e-5f
#define SCAN_BLOCKS ((N_NODES + 255) / 256)   // 196

typedef __attribute__((ext_vector_type(8))) short short8_t;   // 8 bf16 (4 VGPRs)
typedef __attribute__((ext_vector_type(4))) float f32x4;

__device__ __forceinline__ unsigned short f2bf(float f) {
    union { float f; unsigned u; } x; x.f = f;
    unsigned r = x.u + 0x7fffu + ((x.u >> 16) & 1u);   // round-to-nearest-even
    return (unsigned short)(r >> 16);
}
__device__ __forceinline__ float bf2f(unsigned short h) {
    union { unsigned u; float f; } x; x.u = ((unsigned)h) << 16;
    return x.f;
}

// ---------------- degree ----------------
__global__ void deg_kernel(const int* __restrict__ src, const int* __restrict__ dst,
                           int* __restrict__ outdeg, int* __restrict__ indeg) {
    int e = blockIdx.x * 256 + threadIdx.x;
    if (e < N_EDGES) {
        atomicAdd(&outdeg[src[e]], 1);
        atomicAdd(&indeg[dst[e]], 1);
    }
}

__global__ void dis_kernel(const int* __restrict__ outdeg, const int* __restrict__ indeg,
                           float* __restrict__ out_dis, float* __restrict__ in_dis) {
    int i = blockIdx.x * 256 + threadIdx.x;
    if (i < N_NODES) {
        out_dis[i] = rsqrtf(fmaxf((float)outdeg[i], 1.0f));
        in_dis[i]  = rsqrtf(fmaxf((float)indeg[i], 1.0f));
    }
}

// ---------------- hierarchical exclusive scan of indeg -> rowptr/cursor ----------------
__global__ __launch_bounds__(256) void scan1_kernel(const int* __restrict__ indeg,
                                                    int* __restrict__ bsum) {
    __shared__ int lds[256];
    int i = blockIdx.x * 256 + threadIdx.x;
    lds[threadIdx.x] = (i < N_NODES) ? indeg[i] : 0;
    __syncthreads();
    for (int off = 128; off > 0; off >>= 1) {
        if (threadIdx.x < off) lds[threadIdx.x] += lds[threadIdx.x + off];
        __syncthreads();
    }
    if (threadIdx.x == 0) bsum[blockIdx.x] = lds[0];
}

__global__ __launch_bounds__(256) void scan2_kernel(const int* __restrict__ bsum,
                                                    int* __restrict__ boff,
                                                    int* __restrict__ rowptr) {
    __shared__ int lds[256];
    int v = (threadIdx.x < SCAN_BLOCKS) ? bsum[threadIdx.x] : 0;
    lds[threadIdx.x] = v;
    __syncthreads();
    for (int off = 1; off < 256; off <<= 1) {
        int u = (threadIdx.x >= off) ? lds[threadIdx.x - off] : 0;
        __syncthreads();
        lds[threadIdx.x] += u;
        __syncthreads();
    }
    if (threadIdx.x < SCAN_BLOCKS) boff[threadIdx.x] = lds[threadIdx.x] - v;
    if (threadIdx.x == 255) rowptr[N_NODES] = lds[255];
}

__global__ __launch_bounds__(256) void scan3_kernel(const int* __restrict__ indeg,
                                                    const int* __restrict__ boff,
                                                    int* __restrict__ rowptr,
                                                    int* __restrict__ cursor) {
    __shared__ int lds[256];
    int i = blockIdx.x * 256 + threadIdx.x;
    int v = (i < N_NODES) ? indeg[i] : 0;
    lds[threadIdx.x] = v;
    __syncthreads();
    for (int off = 1; off < 256; off <<= 1) {
        int u = (threadIdx.x >= off) ? lds[threadIdx.x - off] : 0;
        __syncthreads();
        lds[threadIdx.x] += u;
        __syncthreads();
    }
    if (i < N_NODES) {
        int ex = boff[blockIdx.x] + lds[threadIdx.x] - v;
        rowptr[i] = ex;
        cursor[i] = ex;
    }
}

__global__ void csr_fill(const int* __restrict__ src, const int* __restrict__ dst,
                         int* __restrict__ cursor, int* __restrict__ csr_src) {
    int e = blockIdx.x * 256 + threadIdx.x;
    if (e < N_EDGES) {
        int pos = atomicAdd(&cursor[dst[e]], 1);
        csr_src[pos] = src[e];
    }
}

// ---------------- weight convert + transpose: W[K][NOUT] f32 -> WT[NOUT][K] bf16 ----------
__global__ void convw_kernel(const float* __restrict__ W, unsigned short* __restrict__ WT,
                             int K, int NOUT) {
    int i = blockIdx.x * 256 + threadIdx.x;
    if (i < K * NOUT) {
        int k = i / NOUT, n = i - k * NOUT;
        WT[(size_t)n * K + k] = f2bf(W[i]);
    }
}

// ---------------- prescale: Xs = bf16(n_feat * out_dis[row]) ----------------
__global__ __launch_bounds__(256) void prescale_kernel(const float* __restrict__ X,
        const float* __restrict__ out_dis, unsigned int* __restrict__ Xs) {
    int i = blockIdx.x * 256 + threadIdx.x;   // over N*64 packed pairs
    if (i < N_NODES * 64) {
        int n = i >> 6;
        float od = out_dis[n];
        float2 v = *reinterpret_cast<const float2*>(X + (size_t)i * 2);
        Xs[i] = (unsigned)f2bf(v.x * od) | ((unsigned)f2bf(v.y * od) << 16);
    }
}

// ---------------- pull aggregation (bf16 in, one wave/node, 2 cols/lane) ----------
// Input X is pre-scaled by out_dis at its producer.
// MODE 0: out = bf16(acc * id)
// MODE 1: out = bf16(relu(acc*id + bias) * od)     (pre-scales for next layer)
template<int MODE>
__global__ __launch_bounds__(256) void pull_agg(const unsigned int* __restrict__ X,
        const int* __restrict__ rowptr, const int* __restrict__ csr_src,
        const float* __restrict__ out_dis, const float* __restrict__ in_dis,
        const float* __restrict__ bias, unsigned int* __restrict__ out) {
    int wave = threadIdx.x >> 6;
    int lane = threadIdx.x & 63;
    int n = blockIdx.x * 4 + wave;
    if (n >= N_NODES) return;
    int beg = rowptr[n], end = rowptr[n + 1];
    float ax = 0.f, ay = 0.f;
    for (int e = beg; e < end; e += 64) {
        int cnt = min(64, end - e);
        int idx = (e + lane < end) ? csr_src[e + lane] : 0;
        int j = 0;
        for (; j + 4 <= cnt; j += 4) {
            int s0 = __shfl(idx, j + 0), s1 = __shfl(idx, j + 1);
            int s2 = __shfl(idx, j + 2), s3 = __shfl(idx, j + 3);
            unsigned u0 = X[(size_t)s0 * 64 + lane];
            unsigned u1 = X[(size_t)s1 * 64 + lane];
            unsigned u2 = X[(size_t)s2 * 64 + lane];
            unsigned u3 = X[(size_t)s3 * 64 + lane];
            ax += bf2f((unsigned short)(u0 & 0xffff)) + bf2f((unsigned short)(u1 & 0xffff))
                + bf2f((unsigned short)(u2 & 0xffff)) + bf2f((unsigned short)(u3 & 0xffff));
            ay += bf2f((unsigned short)(u0 >> 16)) + bf2f((unsigned short)(u1 >> 16))
                + bf2f((unsigned short)(u2 >> 16)) + bf2f((unsigned short)(u3 >> 16));
        }
        for (; j < cnt; j++) {
            int s = __shfl(idx, j);
            unsigned u = X[(size_t)s * 64 + lane];
            ax += bf2f((unsigned short)(u & 0xffff));
            ay += bf2f((unsigned short)(u >> 16));
        }
    }
    float id = in_dis[n];
    float vx = ax * id, vy = ay * id;
    if (MODE == 1) {
        int c2 = lane * 2;
        float od = out_dis[n];
        vx = fmaxf(vx + bias[c2], 0.f) * od;
        vy = fmaxf(vy + bias[c2 + 1], 0.f) * od;
    }
    out[(size_t)n * 64 + lane] = (unsigned)f2bf(vx) | ((unsigned)f2bf(vy) << 16);
}

// ---------------- MFMA bf16 GEMM: out[M,NOUT] = A[M,K] @ W[K,NOUT] ----------------
// A: bf16 [M,K] row-major.  WT: bf16 [NOUT,K] row-major (= W^T).
// EPI 1: bias+relu (aux=bias[NOUT])   EPI 2: row-scale (aux=od[M])
template<int K, int NOUT, int EPI>
__global__ __launch_bounds__(256) void mfma_gemm(const unsigned short* __restrict__ A,
        const unsigned short* __restrict__ WT, const float* __restrict__ aux,
        unsigned short* __restrict__ out) {
    constexpr int NB = NOUT / 16;
    int wave = threadIdx.x >> 6;
    int lane = threadIdx.x & 63;
    int row0 = blockIdx.x * 64 + wave * 16;
    int arow = row0 + (lane & 15);
    int kgrp = (lane >> 4) * 8;

    f32x4 acc[NB];
#pragma unroll
    for (int n = 0; n < NB; n++) acc[n] = f32x4{0.f, 0.f, 0.f, 0.f};

    const unsigned short* wp0 = WT + (size_t)(lane & 15) * K + kgrp;
    for (int kk = 0; kk < K; kk += 32) {
        short8_t a;
        if (arow < N_NODES)
            a = *reinterpret_cast<const short8_t*>(A + (size_t)arow * K + kk + kgrp);
        else
            a = short8_t{0, 0, 0, 0, 0, 0, 0, 0};
        const unsigned short* wp = wp0 + kk;
#pragma unroll
        for (int n = 0; n < NB; n++) {
            short8_t b = *reinterpret_cast<const short8_t*>(wp + (size_t)n * 16 * K);
            acc[n] = __builtin_amdgcn_mfma_f32_16x16x32_bf16(a, b, acc[n], 0, 0, 0);
        }
    }

    // C/D layout: col = lane&15, row = (lane>>4)*4 + reg
    int col0 = lane & 15;
    int rbase = row0 + ((lane >> 4) << 2);
    float rs[4];
    if (EPI == 2) {
#pragma unroll
        for (int j = 0; j < 4; j++)
            rs[j] = (rbase + j < N_NODES) ? aux[rbase + j] : 0.f;
    }
#pragma unroll
    for (int n = 0; n < NB; n++) {
        int col = n * 16 + col0;
        float bv = (EPI == 1) ? aux[col] : 0.f;
#pragma unroll
        for (int j = 0; j < 4; j++) {
            int row = rbase + j;
            if (row < N_NODES) {
                float v = acc[n][j];
                if (EPI == 1) v = fmaxf(v + bv, 0.f);
                if (EPI == 2) v = v * rs[j];
                out[(size_t)row * NOUT + col] = f2bf(v);
            }
        }
    }
}

// ---------------- graph segment boundaries (graph_ids is sorted) ----------------
__global__ void bounds_kernel(const int* __restrict__ gid, int* __restrict__ gstart) {
    int n = blockIdx.x * 256 + threadIdx.x;
    if (n >= N_NODES) return;
    int g = gid[n];
    int gp = (n == 0) ? -1 : gid[n - 1];
    for (int k = gp + 1; k <= g; k++) gstart[k] = n;
    if (n == N_NODES - 1)
        for (int k = g + 1; k <= N_GRAPHS; k++) gstart[k] = N_NODES;
}

// ---------------- sum pooling over contiguous segments (bf16 in, f32 out) ----------
__global__ __launch_bounds__(512) void seg_pool(const unsigned short* __restrict__ X,
        const int* __restrict__ gstart, float* __restrict__ emb) {
    int g = blockIdx.x;
    int c = threadIdx.x & 127;
    int stripe = threadIdx.x >> 7;
    int beg = gstart[g], end = gstart[g + 1];
    float acc = 0.f;
    for (int r = beg + stripe; r < end; r += 4)
        acc += bf2f(X[(size_t)r * 128 + c]);
    __shared__ float buf[4][128];
    buf[stripe][c] = acc;
    __syncthreads();
    if (stripe == 0)
        emb[g * 128 + c] = buf[0][c] + buf[1][c] + buf[2][c] + buf[3][c];
}

// ---------------- batch norm (training stats, biased var) ----------------
__global__ __launch_bounds__(128) void bn_kernel(const float* __restrict__ emb,
        const float* __restrict__ gamma, const float* __restrict__ beta,
        float* __restrict__ bn) {
    int c = threadIdx.x;
    float s = 0.f;
    for (int g = 0; g < N_GRAPHS; g++) s += emb[g * 128 + c];
    float mean = s * (1.0f / N_GRAPHS);
    float v = 0.f;
    for (int g = 0; g < N_GRAPHS; g++) {
        float d = emb[g * 128 + c] - mean;
        v += d * d;
    }
    v *= (1.0f / N_GRAPHS);
    float scale = rsqrtf(v + BN_EPS) * gamma[c];
    float shift = beta[c] - mean * scale;
    for (int g = 0; g < N_GRAPHS; g++)
        bn[g * 128 + c] = emb[g * 128 + c] * scale + shift;
}

// ---------------- FC head + log_softmax ----------------
__global__ __launch_bounds__(128) void fc_kernel(const float* __restrict__ bn,
        const float* __restrict__ Wf1, const float* __restrict__ bf1,
        const float* __restrict__ Wf2, const float* __restrict__ bf2,
        float* __restrict__ out_ls) {
    __shared__ float h[H2];
    __shared__ float logits[OUT_DIM];
    int g = blockIdx.x;
    int j = threadIdx.x;
    const float* bnr = bn + g * H2;
    float acc = bf1[j];
    for (int k = 0; k < H2; k++) acc += bnr[k] * Wf1[k * H2 + j];
    h[j] = fmaxf(acc, 0.f);
    __syncthreads();
    if (j < OUT_DIM) {
        float a2 = bf2[j];
        for (int k = 0; k < H2; k++) a2 += h[k] * Wf2[k * OUT_DIM + j];
        logits[j] = a2;
    }
    __syncthreads();
    if (j < OUT_DIM) {
        float m = -1e30f;
        for (int o = 0; o < OUT_DIM; o++) m = fmaxf(m, logits[o]);
        float se = 0.f;
        for (int o = 0; o < OUT_DIM; o++) se += expf(logits[o] - m);
        out_ls[g * OUT_DIM + j] = logits[j] - m - logf(se);
    }
}

extern "C" void kernel_launch(void* const* d_in, const int* in_sizes, int n_in,
                              void* d_out, int out_size, void* d_ws, size_t ws_size,
                              hipStream_t stream) {
    const float* n_feat = (const float*)d_in[0];
    const int*   src    = (const int*)d_in[1];
    const int*   dst    = (const int*)d_in[2];
    const int*   gid    = (const int*)d_in[3];
    const float* W1     = (const float*)d_in[4];
    const float* b1     = (const float*)d_in[5];
    const float* W2     = (const float*)d_in[6];
    const float* b2     = (const float*)d_in[7];
    const float* W3     = (const float*)d_in[8];
    const float* b3     = (const float*)d_in[9];
    const float* Wf1    = (const float*)d_in[10];
    const float* bf1    = (const float*)d_in[11];
    const float* Wf2    = (const float*)d_in[12];
    const float* bf2    = (const float*)d_in[13];
    const float* gamma  = (const float*)d_in[14];
    const float* beta   = (const float*)d_in[15];
    float* out = (float*)d_out;

    char* ws = (char*)d_ws;
    size_t off = 0;
    auto alloc = [&](size_t bytes) {
        void* p = ws + off;
        off = (off + bytes + 255) & ~(size_t)255;
        return p;
    };
    int*   outdeg  = (int*)  alloc((size_t)N_NODES * 4);
    int*   indeg   = (int*)  alloc((size_t)N_NODES * 4);
    float* out_dis = (float*)alloc((size_t)N_NODES * 4);
    float* in_dis  = (float*)alloc((size_t)N_NODES * 4);
    int*   rowptr  = (int*)  alloc((size_t)(N_NODES + 1) * 4);
    int*   cursor  = (int*)  alloc((size_t)N_NODES * 4);
    int*   bsum    = (int*)  alloc((size_t)SCAN_BLOCKS * 4);
    int*   boff    = (int*)  alloc((size_t)SCAN_BLOCKS * 4);
    int*   gstart  = (int*)  alloc((size_t)(N_GRAPHS + 1) * 4);
    int*   csr_src = (int*)  alloc((size_t)N_EDGES * 4);
    unsigned short* Xs  = (unsigned short*)alloc((size_t)N_NODES * 128 * 2);
    unsigned short* A   = (unsigned short*)alloc((size_t)N_NODES * 256 * 2);
    unsigned short* B   = (unsigned short*)alloc((size_t)N_NODES * 256 * 2);
    unsigned short* W1T = (unsigned short*)alloc((size_t)IN_DIM * HID * 2);
    unsigned short* W2T = (unsigned short*)alloc((size_t)HID * H2 * 2);
    unsigned short* W3T = (unsigned short*)alloc((size_t)H2 * H2 * 2);
    float* bn = (float*)alloc((size_t)N_GRAPHS * H2 * 4);

    hipMemsetAsync(outdeg, 0, (size_t)N_NODES * 4, stream);
    hipMemsetAsync(indeg, 0, (size_t)N_NODES * 4, stream);

    deg_kernel<<<(N_EDGES + 255) / 256, 256, 0, stream>>>(src, dst, outdeg, indeg);
    dis_kernel<<<(N_NODES + 255) / 256, 256, 0, stream>>>(outdeg, indeg, out_dis, in_dis);
    scan1_kernel<<<SCAN_BLOCKS, 256, 0, stream>>>(indeg, bsum);
    scan2_kernel<<<1, 256, 0, stream>>>(bsum, boff, rowptr);
    scan3_kernel<<<SCAN_BLOCKS, 256, 0, stream>>>(indeg, boff, rowptr, cursor);
    csr_fill<<<(N_EDGES + 255) / 256, 256, 0, stream>>>(src, dst, cursor, csr_src);
    bounds_kernel<<<(N_NODES + 255) / 256, 256, 0, stream>>>(gid, gstart);
    convw_kernel<<<(IN_DIM * HID + 255) / 256, 256, 0, stream>>>(W1, W1T, IN_DIM, HID);
    convw_kernel<<<(HID * H2 + 255) / 256, 256, 0, stream>>>(W2, W2T, HID, H2);
    convw_kernel<<<(H2 * H2 + 255) / 256, 256, 0, stream>>>(W3, W3T, H2, H2);
    prescale_kernel<<<(N_NODES * 64 + 255) / 256, 256, 0, stream>>>(n_feat, out_dis,
                                                                    (unsigned int*)Xs);

    const int AGG_GRID = (N_NODES + 3) / 4;
    const int GEMM_GRID = (N_NODES + 63) / 64;

    // Layer 1: A = bf16(agg(Xs)·id); B = bf16(relu(A@W1 + b1))  [N,256]
    pull_agg<0><<<AGG_GRID, 256, 0, stream>>>((unsigned int*)Xs, rowptr, csr_src,
                                              out_dis, in_dis, nullptr, (unsigned int*)A);
    mfma_gemm<128, 256, 1><<<GEMM_GRID, 256, 0, stream>>>(A, W1T, b1, B);

    // Layer 2: A = bf16((X1@W2)·od); B = bf16(relu(agg(A)·id + b2)·od)
    mfma_gemm<256, 128, 2><<<GEMM_GRID, 256, 0, stream>>>(B, W2T, out_dis, A);
    pull_agg<1><<<AGG_GRID, 256, 0, stream>>>((unsigned int*)A, rowptr, csr_src,
                                              out_dis, in_dis, b2, (unsigned int*)B);

    // Layer 3: A = bf16(agg(B)·id); B = bf16(relu(A@W3 + b3))
    pull_agg<0><<<AGG_GRID, 256, 0, stream>>>((unsigned int*)B, rowptr, csr_src,
                                              out_dis, in_dis, nullptr, (unsigned int*)A);
    mfma_gemm<128, 128, 1><<<GEMM_GRID, 256, 0, stream>>>(A, W3T, b3, B);

    // Readout
    seg_pool<<<N_GRAPHS, 512, 0, stream>>>(B, gstart, out);
    bn_kernel<<<1, 128, 0, stream>>>(out, gamma, beta, bn);
    fc_kernel<<<N_GRAPHS, 128, 0, stream>>>(bn, Wf1, bf1, Wf2, bf2, out + (size_t)N_GRAPHS * H2);
}

// Round 5
// 347.049 us; speedup vs baseline: 2.6861x; 1.1822x over previous
//
#include <hip/hip_runtime.h>

#define N_NODES 50000
#define N_EDGES 800000
#define N_GRAPHS 128
#define IN_DIM 128
#define HID 256
#define H2 128
#define OUT_DIM 10
#define BN_EPS 1e-5f

#define SCAN_BLOCKS ((N_NODES + 255) / 256)    // 196
#define EDGE_BLOCKS ((N_EDGES + 255) / 256)    // 3125
#define CW1_BLOCKS  ((IN_DIM * HID) / 256)     // 128
#define CW2_BLOCKS  ((HID * H2) / 256)         // 128
#define CW3_BLOCKS  ((H2 * H2) / 256)          // 64
#define PRESCALE_BLOCKS ((N_NODES * 64 + 255) / 256)   // 12500

typedef __attribute__((ext_vector_type(8))) short short8_t;   // 8 bf16 (4 VGPRs)
typedef __attribute__((ext_vector_type(4))) float f32x4;

__device__ __forceinline__ unsigned short f2bf(float f) {
    union { float f; unsigned u; } x; x.f = f;
    unsigned r = x.u + 0x7fffu + ((x.u >> 16) & 1u);   // round-to-nearest-even
    return (unsigned short)(r >> 16);
}
__device__ __forceinline__ float bf2f(unsigned short h) {
    union { unsigned u; float f; } x; x.u = ((unsigned)h) << 16;
    return x.f;
}

__device__ __forceinline__ void convw_body(const float* __restrict__ W,
        unsigned short* __restrict__ WT, int K, int NOUT, int i) {
    int k = i / NOUT, n = i - k * NOUT;
    WT[(size_t)n * K + k] = f2bf(W[i]);
}

// ---------------- fused preprocessing: edge rank/deg atomics | convw x3 | bounds ----------
__global__ __launch_bounds__(256) void pre_kernel(const int* __restrict__ src,
        const int* __restrict__ dst, int* __restrict__ indeg, int* __restrict__ outdeg,
        int* __restrict__ rank,
        const float* __restrict__ W1, const float* __restrict__ W2, const float* __restrict__ W3,
        unsigned short* __restrict__ W1T, unsigned short* __restrict__ W2T,
        unsigned short* __restrict__ W3T,
        const int* __restrict__ gid, int* __restrict__ gstart) {
    int bid = blockIdx.x, tid = threadIdx.x;
    if (bid < EDGE_BLOCKS) {
        int e = bid * 256 + tid;
        if (e < N_EDGES) {
            rank[e] = atomicAdd(&indeg[dst[e]], 1);
            atomicAdd(&outdeg[src[e]], 1);
        }
        return;
    }
    bid -= EDGE_BLOCKS;
    if (bid < CW1_BLOCKS) { convw_body(W1, W1T, IN_DIM, HID, bid * 256 + tid); return; }
    bid -= CW1_BLOCKS;
    if (bid < CW2_BLOCKS) { convw_body(W2, W2T, HID, H2, bid * 256 + tid); return; }
    bid -= CW2_BLOCKS;
    if (bid < CW3_BLOCKS) { convw_body(W3, W3T, H2, H2, bid * 256 + tid); return; }
    bid -= CW3_BLOCKS;
    {   // bounds: graph segment starts (graph_ids sorted)
        int n = bid * 256 + tid;
        if (n >= N_NODES) return;
        int g = gid[n];
        int gp = (n == 0) ? -1 : gid[n - 1];
        for (int k = gp + 1; k <= g; k++) gstart[k] = n;
        if (n == N_NODES - 1)
            for (int k = g + 1; k <= N_GRAPHS; k++) gstart[k] = N_NODES;
    }
}

// ---------------- scan phase 1 (block sums) fused with prescale ----------------
__global__ __launch_bounds__(256) void scan1_prescale(const int* __restrict__ indeg,
        int* __restrict__ bsum, const float* __restrict__ X,
        const int* __restrict__ outdeg, unsigned int* __restrict__ Xs) {
    int bid = blockIdx.x;
    if (bid < SCAN_BLOCKS) {
        __shared__ int lds[256];
        int i = bid * 256 + threadIdx.x;
        lds[threadIdx.x] = (i < N_NODES) ? indeg[i] : 0;
        __syncthreads();
        for (int off = 128; off > 0; off >>= 1) {
            if (threadIdx.x < off) lds[threadIdx.x] += lds[threadIdx.x + off];
            __syncthreads();
        }
        if (threadIdx.x == 0) bsum[bid] = lds[0];
        return;
    }
    int i = (bid - SCAN_BLOCKS) * 256 + threadIdx.x;   // packed pair index
    if (i < N_NODES * 64) {
        int n = i >> 6;
        float od = rsqrtf(fmaxf((float)outdeg[n], 1.0f));
        float2 v = *reinterpret_cast<const float2*>(X + (size_t)i * 2);
        Xs[i] = (unsigned)f2bf(v.x * od) | ((unsigned)f2bf(v.y * od) << 16);
    }
}

__global__ __launch_bounds__(256) void scan2_kernel(const int* __restrict__ bsum,
                                                    int* __restrict__ boff,
                                                    int* __restrict__ rowptr) {
    __shared__ int lds[256];
    int v = (threadIdx.x < SCAN_BLOCKS) ? bsum[threadIdx.x] : 0;
    lds[threadIdx.x] = v;
    __syncthreads();
    for (int off = 1; off < 256; off <<= 1) {
        int u = (threadIdx.x >= off) ? lds[threadIdx.x - off] : 0;
        __syncthreads();
        lds[threadIdx.x] += u;
        __syncthreads();
    }
    if (threadIdx.x < SCAN_BLOCKS) boff[threadIdx.x] = lds[threadIdx.x] - v;
    if (threadIdx.x == 255) rowptr[N_NODES] = lds[255];
}

__global__ __launch_bounds__(256) void scan3_kernel(const int* __restrict__ indeg,
                                                    const int* __restrict__ boff,
                                                    int* __restrict__ rowptr) {
    __shared__ int lds[256];
    int i = blockIdx.x * 256 + threadIdx.x;
    int v = (i < N_NODES) ? indeg[i] : 0;
    lds[threadIdx.x] = v;
    __syncthreads();
    for (int off = 1; off < 256; off <<= 1) {
        int u = (threadIdx.x >= off) ? lds[threadIdx.x - off] : 0;
        __syncthreads();
        lds[threadIdx.x] += u;
        __syncthreads();
    }
    if (i < N_NODES) rowptr[i] = boff[blockIdx.x] + lds[threadIdx.x] - v;
}

// ---------------- atomic-free CSR scatter ----------------
__global__ __launch_bounds__(256) void scatter_kernel(const int* __restrict__ src,
        const int* __restrict__ dst, const int* __restrict__ rowptr,
        const int* __restrict__ rank, int* __restrict__ csr_src) {
    int e = blockIdx.x * 256 + threadIdx.x;
    if (e < N_EDGES)
        csr_src[rowptr[dst[e]] + rank[e]] = src[e];
}

// ---------------- pull aggregation (bf16 in, one wave/node, 2 cols/lane, 8 in flight) ----
// Input X pre-scaled by out_dis at its producer.
// MODE 0: out = bf16(acc * id)
// MODE 1: out = bf16(relu(acc*id + bias) * od)     (pre-scales for next layer)
template<int MODE>
__global__ __launch_bounds__(256) void pull_agg(const unsigned int* __restrict__ X,
        const int* __restrict__ rowptr, const int* __restrict__ csr_src,
        const int* __restrict__ indeg, const int* __restrict__ outdeg,
        const float* __restrict__ bias, unsigned int* __restrict__ out) {
    int wave = threadIdx.x >> 6;
    int lane = threadIdx.x & 63;
    int n = blockIdx.x * 4 + wave;
    if (n >= N_NODES) return;
    int beg = rowptr[n], end = rowptr[n + 1];
    float ax = 0.f, ay = 0.f;
    for (int e = beg; e < end; e += 64) {
        int cnt = min(64, end - e);
        int idx = (e + lane < end) ? csr_src[e + lane] : 0;
        int j = 0;
        for (; j + 8 <= cnt; j += 8) {
            unsigned u[8];
#pragma unroll
            for (int q = 0; q < 8; q++) {
                int s = __shfl(idx, j + q);
                u[q] = X[(size_t)s * 64 + lane];
            }
#pragma unroll
            for (int q = 0; q < 8; q++) {
                ax += bf2f((unsigned short)(u[q] & 0xffff));
                ay += bf2f((unsigned short)(u[q] >> 16));
            }
        }
        for (; j < cnt; j++) {
            int s = __shfl(idx, j);
            unsigned u = X[(size_t)s * 64 + lane];
            ax += bf2f((unsigned short)(u & 0xffff));
            ay += bf2f((unsigned short)(u >> 16));
        }
    }
    float id = rsqrtf(fmaxf((float)indeg[n], 1.0f));
    float vx = ax * id, vy = ay * id;
    if (MODE == 1) {
        int c2 = lane * 2;
        float od = rsqrtf(fmaxf((float)outdeg[n], 1.0f));
        vx = fmaxf(vx + bias[c2], 0.f) * od;
        vy = fmaxf(vy + bias[c2 + 1], 0.f) * od;
    }
    out[(size_t)n * 64 + lane] = (unsigned)f2bf(vx) | ((unsigned)f2bf(vy) << 16);
}

// ---------------- MFMA bf16 GEMM: out[M,NOUT] = A[M,K] @ W[K,NOUT] ----------------
// A: bf16 [M,K] row-major.  WT: bf16 [NOUT,K] row-major (= W^T).
// EPI 1: bias+relu (aux=bias[NOUT])   EPI 2: row-scale by rsqrt(outdeg) (auxi=outdeg)
template<int K, int NOUT, int EPI>
__global__ __launch_bounds__(256) void mfma_gemm(const unsigned short* __restrict__ A,
        const unsigned short* __restrict__ WT, const float* __restrict__ aux,
        const int* __restrict__ auxi, unsigned short* __restrict__ out) {
    constexpr int NB = NOUT / 16;
    int wave = threadIdx.x >> 6;
    int lane = threadIdx.x & 63;
    int row0 = blockIdx.x * 64 + wave * 16;
    int arow = row0 + (lane & 15);
    int kgrp = (lane >> 4) * 8;

    f32x4 acc[NB];
#pragma unroll
    for (int n = 0; n < NB; n++) acc[n] = f32x4{0.f, 0.f, 0.f, 0.f};

    const unsigned short* wp0 = WT + (size_t)(lane & 15) * K + kgrp;
    for (int kk = 0; kk < K; kk += 32) {
        short8_t a;
        if (arow < N_NODES)
            a = *reinterpret_cast<const short8_t*>(A + (size_t)arow * K + kk + kgrp);
        else
            a = short8_t{0, 0, 0, 0, 0, 0, 0, 0};
        const unsigned short* wp = wp0 + kk;
#pragma unroll
        for (int n = 0; n < NB; n++) {
            short8_t b = *reinterpret_cast<const short8_t*>(wp + (size_t)n * 16 * K);
            acc[n] = __builtin_amdgcn_mfma_f32_16x16x32_bf16(a, b, acc[n], 0, 0, 0);
        }
    }

    // C/D layout: col = lane&15, row = (lane>>4)*4 + reg
    int col0 = lane & 15;
    int rbase = row0 + ((lane >> 4) << 2);
    float rs[4];
    if (EPI == 2) {
#pragma unroll
        for (int j = 0; j < 4; j++)
            rs[j] = (rbase + j < N_NODES) ? rsqrtf(fmaxf((float)auxi[rbase + j], 1.0f)) : 0.f;
    }
#pragma unroll
    for (int n = 0; n < NB; n++) {
        int col = n * 16 + col0;
        float bv = (EPI == 1) ? aux[col] : 0.f;
#pragma unroll
        for (int j = 0; j < 4; j++) {
            int row = rbase + j;
            if (row < N_NODES) {
                float v = acc[n][j];
                if (EPI == 1) v = fmaxf(v + bv, 0.f);
                if (EPI == 2) v = v * rs[j];
                out[(size_t)row * NOUT + col] = f2bf(v);
            }
        }
    }
}

// ---------------- sum pooling over contiguous segments (bf16x2 loads) ----------
__global__ __launch_bounds__(512) void seg_pool(const unsigned int* __restrict__ X,
        const int* __restrict__ gstart, float* __restrict__ emb) {
    int g = blockIdx.x;
    int lane = threadIdx.x & 63;      // 2 cols per lane
    int stripe = threadIdx.x >> 6;    // 0..7
    int beg = gstart[g], end = gstart[g + 1];
    float ax = 0.f, ay = 0.f;
    for (int r = beg + stripe; r < end; r += 8) {
        unsigned u = X[(size_t)r * 64 + lane];
        ax += bf2f((unsigned short)(u & 0xffff));
        ay += bf2f((unsigned short)(u >> 16));
    }
    __shared__ float bufx[8][64], bufy[8][64];
    bufx[stripe][lane] = ax;
    bufy[stripe][lane] = ay;
    __syncthreads();
    if (stripe == 0) {
        float sx = 0.f, sy = 0.f;
#pragma unroll
        for (int q = 0; q < 8; q++) { sx += bufx[q][lane]; sy += bufy[q][lane]; }
        emb[g * 128 + lane * 2]     = sx;
        emb[g * 128 + lane * 2 + 1] = sy;
    }
}

// ---------------- fused BN + FC head + log_softmax ----------------
__global__ __launch_bounds__(128) void fc_kernel(const float* __restrict__ emb,
        const float* __restrict__ gamma, const float* __restrict__ beta,
        const float* __restrict__ Wf1, const float* __restrict__ bf1,
        const float* __restrict__ Wf2, const float* __restrict__ bf2,
        float* __restrict__ out_ls) {
    __shared__ float h[H2];
    __shared__ float logits[OUT_DIM];
    int g = blockIdx.x;
    int j = threadIdx.x;
    // column-j batch stats over all graphs (L2-hot, 64KB)
    float s = 0.f;
    for (int q = 0; q < N_GRAPHS; q++) s += emb[q * 128 + j];
    float mean = s * (1.0f / N_GRAPHS);
    float v = 0.f;
    for (int q = 0; q < N_GRAPHS; q++) {
        float d = emb[q * 128 + j] - mean;
        v += d * d;
    }
    v *= (1.0f / N_GRAPHS);
    float scale = rsqrtf(v + BN_EPS) * gamma[j];
    h[j] = (emb[g * 128 + j] - mean) * scale + beta[j];
    __syncthreads();
    float acc = bf1[j];
    for (int k = 0; k < H2; k++) acc += h[k] * Wf1[k * H2 + j];
    __syncthreads();
    h[j] = fmaxf(acc, 0.f);
    __syncthreads();
    if (j < OUT_DIM) {
        float a2 = bf2[j];
        for (int k = 0; k < H2; k++) a2 += h[k] * Wf2[k * OUT_DIM + j];
        logits[j] = a2;
    }
    __syncthreads();
    if (j < OUT_DIM) {
        float m = -1e30f;
        for (int o = 0; o < OUT_DIM; o++) m = fmaxf(m, logits[o]);
        float se = 0.f;
        for (int o = 0; o < OUT_DIM; o++) se += expf(logits[o] - m);
        out_ls[g * OUT_DIM + j] = logits[j] - m - logf(se);
    }
}

extern "C" void kernel_launch(void* const* d_in, const int* in_sizes, int n_in,
                              void* d_out, int out_size, void* d_ws, size_t ws_size,
                              hipStream_t stream) {
    const float* n_feat = (const float*)d_in[0];
    const int*   src    = (const int*)d_in[1];
    const int*   dst    = (const int*)d_in[2];
    const int*   gid    = (const int*)d_in[3];
    const float* W1     = (const float*)d_in[4];
    const float* b1     = (const float*)d_in[5];
    const float* W2     = (const float*)d_in[6];
    const float* b2     = (const float*)d_in[7];
    const float* W3     = (const float*)d_in[8];
    const float* b3     = (const float*)d_in[9];
    const float* Wf1    = (const float*)d_in[10];
    const float* bf1    = (const float*)d_in[11];
    const float* Wf2    = (const float*)d_in[12];
    const float* bf2    = (const float*)d_in[13];
    const float* gamma  = (const float*)d_in[14];
    const float* beta   = (const float*)d_in[15];
    float* out = (float*)d_out;

    char* ws = (char*)d_ws;
    size_t off = 0;
    auto alloc = [&](size_t bytes) {
        void* p = ws + off;
        off = (off + bytes + 255) & ~(size_t)255;
        return p;
    };
    int* indeg   = (int*)alloc((size_t)N_NODES * 4);
    int* outdeg  = (int*)alloc((size_t)N_NODES * 4);
    int* rank    = (int*)alloc((size_t)N_EDGES * 4);
    int* rowptr  = (int*)alloc((size_t)(N_NODES + 1) * 4);
    int* bsum    = (int*)alloc((size_t)SCAN_BLOCKS * 4);
    int* boff    = (int*)alloc((size_t)SCAN_BLOCKS * 4);
    int* gstart  = (int*)alloc((size_t)(N_GRAPHS + 1) * 4);
    int* csr_src = (int*)alloc((size_t)N_EDGES * 4);
    unsigned short* Xs  = (unsigned short*)alloc((size_t)N_NODES * 128 * 2);
    unsigned short* A   = (unsigned short*)alloc((size_t)N_NODES * 256 * 2);
    unsigned short* B   = (unsigned short*)alloc((size_t)N_NODES * 256 * 2);
    unsigned short* W1T = (unsigned short*)alloc((size_t)IN_DIM * HID * 2);
    unsigned short* W2T = (unsigned short*)alloc((size_t)HID * H2 * 2);
    unsigned short* W3T = (unsigned short*)alloc((size_t)H2 * H2 * 2);

    hipMemsetAsync(indeg, 0, (size_t)N_NODES * 4, stream);
    hipMemsetAsync(outdeg, 0, (size_t)N_NODES * 4, stream);

    // preprocessing: edge atomics (rank+degrees) | weight convert x3 | graph bounds
    pre_kernel<<<EDGE_BLOCKS + CW1_BLOCKS + CW2_BLOCKS + CW3_BLOCKS + SCAN_BLOCKS,
                 256, 0, stream>>>(src, dst, indeg, outdeg, rank,
                                   W1, W2, W3, W1T, W2T, W3T, gid, gstart);
    scan1_prescale<<<SCAN_BLOCKS + PRESCALE_BLOCKS, 256, 0, stream>>>(
        indeg, bsum, n_feat, outdeg, (unsigned int*)Xs);
    scan2_kernel<<<1, 256, 0, stream>>>(bsum, boff, rowptr);
    scan3_kernel<<<SCAN_BLOCKS, 256, 0, stream>>>(indeg, boff, rowptr);
    scatter_kernel<<<EDGE_BLOCKS, 256, 0, stream>>>(src, dst, rowptr, rank, csr_src);

    const int AGG_GRID = (N_NODES + 3) / 4;
    const int GEMM_GRID = (N_NODES + 63) / 64;

    // Layer 1: A = bf16(agg(Xs)·id); B = bf16(relu(A@W1 + b1))  [N,256]
    pull_agg<0><<<AGG_GRID, 256, 0, stream>>>((unsigned int*)Xs, rowptr, csr_src,
                                              indeg, outdeg, nullptr, (unsigned int*)A);
    mfma_gemm<128, 256, 1><<<GEMM_GRID, 256, 0, stream>>>(A, W1T, b1, nullptr, B);

    // Layer 2: A = bf16((X1@W2)·od); B = bf16(relu(agg(A)·id + b2)·od)
    mfma_gemm<256, 128, 2><<<GEMM_GRID, 256, 0, stream>>>(B, W2T, nullptr, outdeg, A);
    pull_agg<1><<<AGG_GRID, 256, 0, stream>>>((unsigned int*)A, rowptr, csr_src,
                                              indeg, outdeg, b2, (unsigned int*)B);

    // Layer 3: A = bf16(agg(B)·id); B = bf16(relu(A@W3 + b3))
    pull_agg<0><<<AGG_GRID, 256, 0, stream>>>((unsigned int*)B, rowptr, csr_src,
                                              indeg, outdeg, nullptr, (unsigned int*)A);
    mfma_gemm<128, 128, 1><<<GEMM_GRID, 256, 0, stream>>>(A, W3T, b3, nullptr, B);

    // Readout: segmented pooling, fused BN+FC+log_softmax
    seg_pool<<<N_GRAPHS, 512, 0, stream>>>((unsigned int*)B, gstart, out);
    fc_kernel<<<N_GRAPHS, 128, 0, stream>>>(out, gamma, beta, Wf1, bf1, Wf2, bf2,
                                            out + (size_t)N_GRAPHS * H2);
}

// Round 6
// 320.622 us; speedup vs baseline: 2.9075x; 1.0824x over previous
//
#include <hip/hip_runtime.h>

#define N_NODES 50000
#define N_EDGES 800000
#define N_GRAPHS 128
#define IN_DIM 128
#define HID 256
#define H2 128
#define OUT_DIM 10
#define BN_EPS 1e-5f

#define NBUCK 196                              // dst>>8 buckets (50000/256)
#define K1_ITEMS 2048
#define NB_EDGE ((N_EDGES + K1_ITEMS - 1) / K1_ITEMS)   // 391
#define BND_BLOCKS ((N_NODES + 255) / 256)     // 196
#define CW1_BLOCKS  ((IN_DIM * HID) / 256)     // 128
#define CW2_BLOCKS  ((HID * H2) / 256)         // 128
#define CW3_BLOCKS  ((H2 * H2) / 256)          // 64

typedef __attribute__((ext_vector_type(8))) short short8_t;   // 8 bf16 (4 VGPRs)
typedef __attribute__((ext_vector_type(4))) float f32x4;

__device__ __forceinline__ unsigned short f2bf(float f) {
    union { float f; unsigned u; } x; x.f = f;
    unsigned r = x.u + 0x7fffu + ((x.u >> 16) & 1u);   // round-to-nearest-even
    return (unsigned short)(r >> 16);
}
__device__ __forceinline__ float bf2f(unsigned short h) {
    union { unsigned u; float f; } x; x.u = ((unsigned)h) << 16;
    return x.f;
}
__device__ __forceinline__ unsigned pack2(float a, float b) {
    return (unsigned)f2bf(a) | ((unsigned)f2bf(b) << 16);
}

__device__ __forceinline__ void convw_body(const float* __restrict__ W,
        unsigned short* __restrict__ WT, int K, int NOUT, int i) {
    int k = i / NOUT, n = i - k * NOUT;
    WT[(size_t)n * K + k] = f2bf(W[i]);
}

// ---- K1: per-block LDS histograms of dst>>8 and src>>8 | convw x3 | graph bounds ----
__global__ __launch_bounds__(256) void k1_hist(const int* __restrict__ src,
        const int* __restrict__ dst, int* __restrict__ cntD, int* __restrict__ cntS,
        const float* __restrict__ W1, const float* __restrict__ W2, const float* __restrict__ W3,
        unsigned short* __restrict__ W1T, unsigned short* __restrict__ W2T,
        unsigned short* __restrict__ W3T,
        const int* __restrict__ gid, int* __restrict__ gstart) {
    int bid = blockIdx.x, tid = threadIdx.x;
    if (bid < NB_EDGE) {
        __shared__ int hD[256], hS[256];
        hD[tid] = 0; hS[tid] = 0;
        __syncthreads();
        int base = bid * K1_ITEMS;
#pragma unroll
        for (int it = 0; it < 8; it++) {
            int e = base + it * 256 + tid;
            if (e < N_EDGES) {
                atomicAdd(&hD[dst[e] >> 8], 1);
                atomicAdd(&hS[src[e] >> 8], 1);
            }
        }
        __syncthreads();
        cntD[bid * 256 + tid] = hD[tid];
        cntS[bid * 256 + tid] = hS[tid];
        return;
    }
    bid -= NB_EDGE;
    if (bid < CW1_BLOCKS) { convw_body(W1, W1T, IN_DIM, HID, bid * 256 + tid); return; }
    bid -= CW1_BLOCKS;
    if (bid < CW2_BLOCKS) { convw_body(W2, W2T, HID, H2, bid * 256 + tid); return; }
    bid -= CW2_BLOCKS;
    if (bid < CW3_BLOCKS) { convw_body(W3, W3T, H2, H2, bid * 256 + tid); return; }
    bid -= CW3_BLOCKS;
    {   // graph segment starts (graph_ids sorted)
        int n = bid * 256 + tid;
        if (n >= N_NODES) return;
        int g = gid[n];
        int gp = (n == 0) ? -1 : gid[n - 1];
        for (int k = gp + 1; k <= g; k++) gstart[k] = n;
        if (n == N_NODES - 1)
            for (int k = g + 1; k <= N_GRAPHS; k++) gstart[k] = N_NODES;
    }
}

// ---- K2: scan count tables -> per-(block,bucket) offsets + bucket bases ----
__global__ __launch_bounds__(256) void k2_scan(const int* __restrict__ cntD,
        const int* __restrict__ cntS, int* __restrict__ offD, int* __restrict__ offS,
        int* __restrict__ baseD, int* __restrict__ baseS, int* __restrict__ rowptr) {
    int b = threadIdx.x;
    int runD = 0, runS = 0;
    for (int blk = 0; blk < NB_EDGE; blk++) {
        int cD = cntD[blk * 256 + b]; offD[blk * 256 + b] = runD; runD += cD;
        int cS = cntS[blk * 256 + b]; offS[blk * 256 + b] = runS; runS += cS;
    }
    __shared__ int ldsD[256], ldsS[256];
    ldsD[b] = runD; ldsS[b] = runS;
    __syncthreads();
    for (int off = 1; off < 256; off <<= 1) {
        int uD = (b >= off) ? ldsD[b - off] : 0;
        int uS = (b >= off) ? ldsS[b - off] : 0;
        __syncthreads();
        ldsD[b] += uD; ldsS[b] += uS;
        __syncthreads();
    }
    baseD[b] = ldsD[b] - runD;
    baseS[b] = ldsS[b] - runS;
    if (b == 0) rowptr[N_NODES] = N_EDGES;
}

// ---- K3: scatter edges into dst-buckets (uint2{dst,src}) and src-buckets (src) ----
__global__ __launch_bounds__(256) void k3_scatter(const int* __restrict__ src,
        const int* __restrict__ dst, const int* __restrict__ offD, const int* __restrict__ offS,
        const int* __restrict__ baseD, const int* __restrict__ baseS,
        uint2* __restrict__ bufD, int* __restrict__ bufS) {
    __shared__ int cD[256], cS[256];
    int bid = blockIdx.x, tid = threadIdx.x;
    cD[tid] = baseD[tid] + offD[bid * 256 + tid];
    cS[tid] = baseS[tid] + offS[bid * 256 + tid];
    __syncthreads();
    int base = bid * K1_ITEMS;
#pragma unroll
    for (int it = 0; it < 8; it++) {
        int e = base + it * 256 + tid;
        if (e < N_EDGES) {
            int d = dst[e], s = src[e];
            int pd = atomicAdd(&cD[d >> 8], 1);
            bufD[pd] = make_uint2((unsigned)d, (unsigned)s);
            int ps = atomicAdd(&cS[s >> 8], 1);
            bufS[ps] = s;
        }
    }
}

// ---- K4: per dst-bucket: indeg, rowptr, csr_src (contiguous streams, LDS only) ----
__global__ __launch_bounds__(256) void k4_csr(const uint2* __restrict__ bufD,
        const int* __restrict__ baseD, int* __restrict__ indeg,
        int* __restrict__ rowptr, int* __restrict__ csr_src) {
    __shared__ int cnt[256], lds[256], curs[256];
    int b = blockIdx.x, t = threadIdx.x;
    int eb = baseD[b], ee = baseD[b + 1];
    cnt[t] = 0;
    __syncthreads();
    for (int e = eb + t; e < ee; e += 256)
        atomicAdd(&cnt[bufD[e].x & 255], 1);
    __syncthreads();
    int v = cnt[t];
    lds[t] = v;
    __syncthreads();
    for (int off = 1; off < 256; off <<= 1) {
        int u = (t >= off) ? lds[t - off] : 0;
        __syncthreads();
        lds[t] += u;
        __syncthreads();
    }
    int n0 = b << 8;
    int ex = eb + lds[t] - v;
    if (n0 + t < N_NODES) {
        indeg[n0 + t] = v;
        rowptr[n0 + t] = ex;
    }
    curs[t] = ex;
    __syncthreads();
    for (int e = eb + t; e < ee; e += 256) {
        uint2 ed = bufD[e];
        int slot = atomicAdd(&curs[ed.x & 255], 1);
        csr_src[slot] = (int)ed.y;
    }
}

// ---- K5: per src-bucket: outdeg histogram + fused n_feat prescale -> Xs bf16 ----
__global__ __launch_bounds__(256) void k5_outdeg_prescale(const int* __restrict__ bufS,
        const int* __restrict__ baseS, const float* __restrict__ n_feat,
        int* __restrict__ outdeg, unsigned int* __restrict__ Xs) {
    __shared__ int cnt[256];
    __shared__ float od[256];
    int b = blockIdx.x, t = threadIdx.x;
    int eb = baseS[b], ee = baseS[b + 1];
    cnt[t] = 0;
    __syncthreads();
    for (int e = eb + t; e < ee; e += 256)
        atomicAdd(&cnt[bufS[e] & 255], 1);
    __syncthreads();
    int n0 = b << 8;
    int nn = min(256, N_NODES - n0);
    if (t < nn) outdeg[n0 + t] = cnt[t];
    od[t] = rsqrtf(fmaxf((float)cnt[t], 1.0f));
    __syncthreads();
    int pc = t & 127;       // pair-column
    int rh = t >> 7;        // row parity
    for (int r = rh; r < nn; r += 2) {
        int row = n0 + r;
        float2 v = *reinterpret_cast<const float2*>(n_feat + (size_t)row * 128 + pc * 2);
        float s = od[r];
        Xs[(size_t)row * 64 + pc] = pack2(v.x * s, v.y * s);
    }
}

// ---- pull aggregation: wave/node, paired rows, 8B/lane, scalar indices ----
// MODE 0: out = bf16(acc * id)
// MODE 1: out = bf16(relu(acc*id + bias) * od)   (pre-scales for next layer)
template<int MODE>
__global__ __launch_bounds__(256) void pull_agg(const unsigned int* __restrict__ X,
        const int* __restrict__ rowptr, const int* __restrict__ csr_src,
        const int* __restrict__ indeg, const int* __restrict__ outdeg,
        const float* __restrict__ bias, unsigned int* __restrict__ out) {
    int lane = threadIdx.x & 63;
    int n = blockIdx.x * 4 + (threadIdx.x >> 6);
    n = __builtin_amdgcn_readfirstlane(n);     // force SGPR: scalar loads below
    if (n >= N_NODES) return;
    int l32 = lane & 31;
    int half = lane >> 5;
    int beg = rowptr[n];
    int cnt = rowptr[n + 1] - beg;
    const int* ep = csr_src + beg;
    float a0 = 0.f, a1 = 0.f, a2 = 0.f, a3 = 0.f;
    int voff = l32 << 1;

    auto acc = [&](uint2 u) {
        a0 += bf2f((unsigned short)(u.x & 0xffff));
        a1 += bf2f((unsigned short)(u.x >> 16));
        a2 += bf2f((unsigned short)(u.y & 0xffff));
        a3 += bf2f((unsigned short)(u.y >> 16));
    };

    int j = 0;
    for (; j + 8 <= cnt; j += 8) {
        uint2 u[4];
#pragma unroll
        for (int q = 0; q < 4; q++) {
            int sa = ep[j + 2 * q], sb = ep[j + 2 * q + 1];
            int s = half ? sb : sa;
            u[q] = *reinterpret_cast<const uint2*>(X + ((size_t)s << 6) + voff);
        }
#pragma unroll
        for (int q = 0; q < 4; q++) acc(u[q]);
    }
    for (; j + 2 <= cnt; j += 2) {
        int sa = ep[j], sb = ep[j + 1];
        int s = half ? sb : sa;
        acc(*reinterpret_cast<const uint2*>(X + ((size_t)s << 6) + voff));
    }
    if (j < cnt && half == 0) {
        int s = ep[j];
        acc(*reinterpret_cast<const uint2*>(X + ((size_t)s << 6) + voff));
    }

    a0 += __shfl_xor(a0, 32);
    a1 += __shfl_xor(a1, 32);
    a2 += __shfl_xor(a2, 32);
    a3 += __shfl_xor(a3, 32);

    if (lane < 32) {
        float id = rsqrtf(fmaxf((float)indeg[n], 1.0f));
        float v0 = a0 * id, v1 = a1 * id, v2 = a2 * id, v3 = a3 * id;
        if (MODE == 1) {
            float odv = rsqrtf(fmaxf((float)outdeg[n], 1.0f));
            float4 bv = *reinterpret_cast<const float4*>(bias + l32 * 4);
            v0 = fmaxf(v0 + bv.x, 0.f) * odv;
            v1 = fmaxf(v1 + bv.y, 0.f) * odv;
            v2 = fmaxf(v2 + bv.z, 0.f) * odv;
            v3 = fmaxf(v3 + bv.w, 0.f) * odv;
        }
        uint2 o = make_uint2(pack2(v0, v1), pack2(v2, v3));
        *reinterpret_cast<uint2*>(out + (size_t)n * 64 + voff) = o;
    }
}

// ---------------- MFMA bf16 GEMM: out[M,NOUT] = A[M,K] @ W[K,NOUT] ----------------
// EPI 1: bias+relu (aux=bias[NOUT])   EPI 2: row-scale by rsqrt(outdeg) (auxi=outdeg)
template<int K, int NOUT, int EPI>
__global__ __launch_bounds__(256) void mfma_gemm(const unsigned short* __restrict__ A,
        const unsigned short* __restrict__ WT, const float* __restrict__ aux,
        const int* __restrict__ auxi, unsigned short* __restrict__ out) {
    constexpr int NB = NOUT / 16;
    int wave = threadIdx.x >> 6;
    int lane = threadIdx.x & 63;
    int row0 = blockIdx.x * 64 + wave * 16;
    int arow = row0 + (lane & 15);
    int kgrp = (lane >> 4) * 8;

    f32x4 acc[NB];
#pragma unroll
    for (int n = 0; n < NB; n++) acc[n] = f32x4{0.f, 0.f, 0.f, 0.f};

    const unsigned short* wp0 = WT + (size_t)(lane & 15) * K + kgrp;
    for (int kk = 0; kk < K; kk += 32) {
        short8_t a;
        if (arow < N_NODES)
            a = *reinterpret_cast<const short8_t*>(A + (size_t)arow * K + kk + kgrp);
        else
            a = short8_t{0, 0, 0, 0, 0, 0, 0, 0};
        const unsigned short* wp = wp0 + kk;
#pragma unroll
        for (int n = 0; n < NB; n++) {
            short8_t b = *reinterpret_cast<const short8_t*>(wp + (size_t)n * 16 * K);
            acc[n] = __builtin_amdgcn_mfma_f32_16x16x32_bf16(a, b, acc[n], 0, 0, 0);
        }
    }

    // C/D layout: col = lane&15, row = (lane>>4)*4 + reg
    int col0 = lane & 15;
    int rbase = row0 + ((lane >> 4) << 2);
    float rs[4];
    if (EPI == 2) {
#pragma unroll
        for (int j = 0; j < 4; j++)
            rs[j] = (rbase + j < N_NODES) ? rsqrtf(fmaxf((float)auxi[rbase + j], 1.0f)) : 0.f;
    }
#pragma unroll
    for (int n = 0; n < NB; n++) {
        int col = n * 16 + col0;
        float bv = (EPI == 1) ? aux[col] : 0.f;
#pragma unroll
        for (int j = 0; j < 4; j++) {
            int row = rbase + j;
            if (row < N_NODES) {
                float v = acc[n][j];
                if (EPI == 1) v = fmaxf(v + bv, 0.f);
                if (EPI == 2) v = v * rs[j];
                out[(size_t)row * NOUT + col] = f2bf(v);
            }
        }
    }
}

// ---------------- sum pooling over contiguous segments (bf16x2 loads) ----------
__global__ __launch_bounds__(512) void seg_pool(const unsigned int* __restrict__ X,
        const int* __restrict__ gstart, float* __restrict__ emb) {
    int g = blockIdx.x;
    int lane = threadIdx.x & 63;
    int stripe = threadIdx.x >> 6;
    int beg = gstart[g], end = gstart[g + 1];
    float ax = 0.f, ay = 0.f;
    for (int r = beg + stripe; r < end; r += 8) {
        unsigned u = X[(size_t)r * 64 + lane];
        ax += bf2f((unsigned short)(u & 0xffff));
        ay += bf2f((unsigned short)(u >> 16));
    }
    __shared__ float bufx[8][64], bufy[8][64];
    bufx[stripe][lane] = ax;
    bufy[stripe][lane] = ay;
    __syncthreads();
    if (stripe == 0) {
        float sx = 0.f, sy = 0.f;
#pragma unroll
        for (int q = 0; q < 8; q++) { sx += bufx[q][lane]; sy += bufy[q][lane]; }
        emb[g * 128 + lane * 2]     = sx;
        emb[g * 128 + lane * 2 + 1] = sy;
    }
}

// ---------------- fused BN + FC head + log_softmax ----------------
__global__ __launch_bounds__(128) void fc_kernel(const float* __restrict__ emb,
        const float* __restrict__ gamma, const float* __restrict__ beta,
        const float* __restrict__ Wf1, const float* __restrict__ bf1,
        const float* __restrict__ Wf2, const float* __restrict__ bf2,
        float* __restrict__ out_ls) {
    __shared__ float h[H2];
    __shared__ float logits[OUT_DIM];
    int g = blockIdx.x;
    int j = threadIdx.x;
    float s = 0.f;
    for (int q = 0; q < N_GRAPHS; q++) s += emb[q * 128 + j];
    float mean = s * (1.0f / N_GRAPHS);
    float v = 0.f;
    for (int q = 0; q < N_GRAPHS; q++) {
        float d = emb[q * 128 + j] - mean;
        v += d * d;
    }
    v *= (1.0f / N_GRAPHS);
    float scale = rsqrtf(v + BN_EPS) * gamma[j];
    h[j] = (emb[g * 128 + j] - mean) * scale + beta[j];
    __syncthreads();
    float acc = bf1[j];
    for (int k = 0; k < H2; k++) acc += h[k] * Wf1[k * H2 + j];
    __syncthreads();
    h[j] = fmaxf(acc, 0.f);
    __syncthreads();
    if (j < OUT_DIM) {
        float a2 = bf2[j];
        for (int k = 0; k < H2; k++) a2 += h[k] * Wf2[k * OUT_DIM + j];
        logits[j] = a2;
    }
    __syncthreads();
    if (j < OUT_DIM) {
        float m = -1e30f;
        for (int o = 0; o < OUT_DIM; o++) m = fmaxf(m, logits[o]);
        float se = 0.f;
        for (int o = 0; o < OUT_DIM; o++) se += expf(logits[o] - m);
        out_ls[g * OUT_DIM + j] = logits[j] - m - logf(se);
    }
}

extern "C" void kernel_launch(void* const* d_in, const int* in_sizes, int n_in,
                              void* d_out, int out_size, void* d_ws, size_t ws_size,
                              hipStream_t stream) {
    const float* n_feat = (const float*)d_in[0];
    const int*   src    = (const int*)d_in[1];
    const int*   dst    = (const int*)d_in[2];
    const int*   gid    = (const int*)d_in[3];
    const float* W1     = (const float*)d_in[4];
    const float* b1     = (const float*)d_in[5];
    const float* W2     = (const float*)d_in[6];
    const float* b2     = (const float*)d_in[7];
    const float* W3     = (const float*)d_in[8];
    const float* b3     = (const float*)d_in[9];
    const float* Wf1    = (const float*)d_in[10];
    const float* bf1    = (const float*)d_in[11];
    const float* Wf2    = (const float*)d_in[12];
    const float* bf2    = (const float*)d_in[13];
    const float* gamma  = (const float*)d_in[14];
    const float* beta   = (const float*)d_in[15];
    float* out = (float*)d_out;

    char* ws = (char*)d_ws;
    size_t off = 0;
    auto alloc = [&](size_t bytes) {
        void* p = ws + off;
        off = (off + bytes + 255) & ~(size_t)255;
        return p;
    };
    int* cntD    = (int*)alloc((size_t)NB_EDGE * 256 * 4);
    int* cntS    = (int*)alloc((size_t)NB_EDGE * 256 * 4);
    int* offD    = (int*)alloc((size_t)NB_EDGE * 256 * 4);
    int* offS    = (int*)alloc((size_t)NB_EDGE * 256 * 4);
    int* baseD   = (int*)alloc(257 * 4);
    int* baseS   = (int*)alloc(257 * 4);
    int* indeg   = (int*)alloc((size_t)N_NODES * 4);
    int* outdeg  = (int*)alloc((size_t)N_NODES * 4);
    int* rowptr  = (int*)alloc((size_t)(N_NODES + 1) * 4);
    int* gstart  = (int*)alloc((size_t)(N_GRAPHS + 1) * 4);
    uint2* bufD  = (uint2*)alloc((size_t)N_EDGES * 8);
    int* bufS    = (int*)alloc((size_t)N_EDGES * 4);
    int* csr_src = (int*)alloc((size_t)N_EDGES * 4);
    unsigned short* Xs  = (unsigned short*)alloc((size_t)N_NODES * 128 * 2);
    unsigned short* A   = (unsigned short*)alloc((size_t)N_NODES * 128 * 2);
    unsigned short* B   = (unsigned short*)alloc((size_t)N_NODES * 256 * 2);
    unsigned short* W1T = (unsigned short*)alloc((size_t)IN_DIM * HID * 2);
    unsigned short* W2T = (unsigned short*)alloc((size_t)HID * H2 * 2);
    unsigned short* W3T = (unsigned short*)alloc((size_t)H2 * H2 * 2);

    // preprocessing: zero global atomics
    k1_hist<<<NB_EDGE + CW1_BLOCKS + CW2_BLOCKS + CW3_BLOCKS + BND_BLOCKS, 256, 0, stream>>>(
        src, dst, cntD, cntS, W1, W2, W3, W1T, W2T, W3T, gid, gstart);
    k2_scan<<<1, 256, 0, stream>>>(cntD, cntS, offD, offS, baseD, baseS, rowptr);
    k3_scatter<<<NB_EDGE, 256, 0, stream>>>(src, dst, offD, offS, baseD, baseS, bufD, bufS);
    k4_csr<<<NBUCK, 256, 0, stream>>>(bufD, baseD, indeg, rowptr, csr_src);
    k5_outdeg_prescale<<<NBUCK, 256, 0, stream>>>(bufS, baseS, n_feat, outdeg,
                                                  (unsigned int*)Xs);

    const int AGG_GRID = (N_NODES + 3) / 4;
    const int GEMM_GRID = (N_NODES + 63) / 64;

    // Layer 1: A = bf16(agg(Xs)·id); B = bf16(relu(A@W1 + b1))  [N,256]
    pull_agg<0><<<AGG_GRID, 256, 0, stream>>>((unsigned int*)Xs, rowptr, csr_src,
                                              indeg, outdeg, nullptr, (unsigned int*)A);
    mfma_gemm<128, 256, 1><<<GEMM_GRID, 256, 0, stream>>>(A, W1T, b1, nullptr, B);

    // Layer 2: A = bf16((X1@W2)·od); B = bf16(relu(agg(A)·id + b2)·od)
    mfma_gemm<256, 128, 2><<<GEMM_GRID, 256, 0, stream>>>(B, W2T, nullptr, outdeg, A);
    pull_agg<1><<<AGG_GRID, 256, 0, stream>>>((unsigned int*)A, rowptr, csr_src,
                                              indeg, outdeg, b2, (unsigned int*)B);

    // Layer 3: A = bf16(agg(B)·id); B = bf16(relu(A@W3 + b3))
    pull_agg<0><<<AGG_GRID, 256, 0, stream>>>((unsigned int*)B, rowptr, csr_src,
                                              indeg, outdeg, nullptr, (unsigned int*)A);
    mfma_gemm<128, 128, 1><<<GEMM_GRID, 256, 0, stream>>>(A, W3T, b3, nullptr, B);

    // Readout
    seg_pool<<<N_GRAPHS, 512, 0, stream>>>((unsigned int*)B, gstart, out);
    fc_kernel<<<N_GRAPHS, 128, 0, stream>>>(out, gamma, beta, Wf1, bf1, Wf2, bf2,
                                            out + (size_t)N_GRAPHS * H2);
}

// Round 7
// 265.161 us; speedup vs baseline: 3.5156x; 1.2092x over previous
//
#include <hip/hip_runtime.h>

#define N_NODES 50000
#define N_EDGES 800000
#define N_GRAPHS 128
#define IN_DIM 128
#define HID 256
#define H2 128
#define OUT_DIM 10
#define BN_EPS 1e-5f

#define NBUCK 196                              // dst>>8 buckets (50000/256)
#define K1_ITEMS 2048
#define NB_EDGE ((N_EDGES + K1_ITEMS - 1) / K1_ITEMS)   // 391
#define BND_BLOCKS ((N_NODES + 255) / 256)     // 196
#define CW1_BLOCKS  ((IN_DIM * HID) / 256)     // 128
#define CW2_BLOCKS  ((HID * H2) / 256)         // 128
#define CW3_BLOCKS  ((H2 * H2) / 256)          // 64

typedef __attribute__((ext_vector_type(8))) short short8_t;   // 8 bf16 (4 VGPRs)
typedef __attribute__((ext_vector_type(4))) float f32x4;

__device__ __forceinline__ unsigned short f2bf(float f) {
    union { float f; unsigned u; } x; x.f = f;
    unsigned r = x.u + 0x7fffu + ((x.u >> 16) & 1u);   // round-to-nearest-even
    return (unsigned short)(r >> 16);
}
__device__ __forceinline__ float bf2f(unsigned short h) {
    union { unsigned u; float f; } x; x.u = ((unsigned)h) << 16;
    return x.f;
}
__device__ __forceinline__ unsigned pack2(float a, float b) {
    return (unsigned)f2bf(a) | ((unsigned)f2bf(b) << 16);
}

__device__ __forceinline__ void convw_body(const float* __restrict__ W,
        unsigned short* __restrict__ WT, int K, int NOUT, int i) {
    int k = i / NOUT, n = i - k * NOUT;
    WT[(size_t)n * K + k] = f2bf(W[i]);
}

// ---- K1: per-block LDS histograms of dst>>8 and src>>8 | convw x3 | graph bounds ----
__global__ __launch_bounds__(256) void k1_hist(const int* __restrict__ src,
        const int* __restrict__ dst, int* __restrict__ cntD, int* __restrict__ cntS,
        const float* __restrict__ W1, const float* __restrict__ W2, const float* __restrict__ W3,
        unsigned short* __restrict__ W1T, unsigned short* __restrict__ W2T,
        unsigned short* __restrict__ W3T,
        const int* __restrict__ gid, int* __restrict__ gstart) {
    int bid = blockIdx.x, tid = threadIdx.x;
    if (bid < NB_EDGE) {
        __shared__ int hD[256], hS[256];
        hD[tid] = 0; hS[tid] = 0;
        __syncthreads();
        int base = bid * K1_ITEMS;
#pragma unroll
        for (int it = 0; it < 8; it++) {
            int e = base + it * 256 + tid;
            if (e < N_EDGES) {
                atomicAdd(&hD[dst[e] >> 8], 1);
                atomicAdd(&hS[src[e] >> 8], 1);
            }
        }
        __syncthreads();
        cntD[bid * 256 + tid] = hD[tid];
        cntS[bid * 256 + tid] = hS[tid];
        return;
    }
    bid -= NB_EDGE;
    if (bid < CW1_BLOCKS) { convw_body(W1, W1T, IN_DIM, HID, bid * 256 + tid); return; }
    bid -= CW1_BLOCKS;
    if (bid < CW2_BLOCKS) { convw_body(W2, W2T, HID, H2, bid * 256 + tid); return; }
    bid -= CW2_BLOCKS;
    if (bid < CW3_BLOCKS) { convw_body(W3, W3T, H2, H2, bid * 256 + tid); return; }
    bid -= CW3_BLOCKS;
    {   // graph segment starts (graph_ids sorted)
        int n = bid * 256 + tid;
        if (n >= N_NODES) return;
        int g = gid[n];
        int gp = (n == 0) ? -1 : gid[n - 1];
        for (int k = gp + 1; k <= g; k++) gstart[k] = n;
        if (n == N_NODES - 1)
            for (int k = g + 1; k <= N_GRAPHS; k++) gstart[k] = N_NODES;
    }
}

// ---- K2: scan count tables -> per-(block,bucket) offsets + bucket bases ----
__global__ __launch_bounds__(256) void k2_scan(const int* __restrict__ cntD,
        const int* __restrict__ cntS, int* __restrict__ offD, int* __restrict__ offS,
        int* __restrict__ baseD, int* __restrict__ baseS, int* __restrict__ rowptr) {
    int b = threadIdx.x;
    int runD = 0, runS = 0;
    for (int blk = 0; blk < NB_EDGE; blk++) {
        int cD = cntD[blk * 256 + b]; offD[blk * 256 + b] = runD; runD += cD;
        int cS = cntS[blk * 256 + b]; offS[blk * 256 + b] = runS; runS += cS;
    }
    __shared__ int ldsD[256], ldsS[256];
    ldsD[b] = runD; ldsS[b] = runS;
    __syncthreads();
    for (int off = 1; off < 256; off <<= 1) {
        int uD = (b >= off) ? ldsD[b - off] : 0;
        int uS = (b >= off) ? ldsS[b - off] : 0;
        __syncthreads();
        ldsD[b] += uD; ldsS[b] += uS;
        __syncthreads();
    }
    baseD[b] = ldsD[b] - runD;
    baseS[b] = ldsS[b] - runS;
    if (b == 0) rowptr[N_NODES] = N_EDGES;
}

// ---- K3: scatter edges into dst-buckets (uint2{dst,src}) and src-buckets (src) ----
__global__ __launch_bounds__(256) void k3_scatter(const int* __restrict__ src,
        const int* __restrict__ dst, const int* __restrict__ offD, const int* __restrict__ offS,
        const int* __restrict__ baseD, const int* __restrict__ baseS,
        uint2* __restrict__ bufD, int* __restrict__ bufS) {
    __shared__ int cD[256], cS[256];
    int bid = blockIdx.x, tid = threadIdx.x;
    cD[tid] = baseD[tid] + offD[bid * 256 + tid];
    cS[tid] = baseS[tid] + offS[bid * 256 + tid];
    __syncthreads();
    int base = bid * K1_ITEMS;
#pragma unroll
    for (int it = 0; it < 8; it++) {
        int e = base + it * 256 + tid;
        if (e < N_EDGES) {
            int d = dst[e], s = src[e];
            int pd = atomicAdd(&cD[d >> 8], 1);
            bufD[pd] = make_uint2((unsigned)d, (unsigned)s);
            int ps = atomicAdd(&cS[s >> 8], 1);
            bufS[ps] = s;
        }
    }
}

// ---- K4: per dst-bucket: indeg, rowptr, csr_src (contiguous streams, LDS only) ----
__global__ __launch_bounds__(256) void k4_csr(const uint2* __restrict__ bufD,
        const int* __restrict__ baseD, int* __restrict__ indeg,
        int* __restrict__ rowptr, int* __restrict__ csr_src) {
    __shared__ int cnt[256], lds[256], curs[256];
    int b = blockIdx.x, t = threadIdx.x;
    int eb = baseD[b], ee = baseD[b + 1];
    cnt[t] = 0;
    __syncthreads();
    for (int e = eb + t; e < ee; e += 256)
        atomicAdd(&cnt[bufD[e].x & 255], 1);
    __syncthreads();
    int v = cnt[t];
    lds[t] = v;
    __syncthreads();
    for (int off = 1; off < 256; off <<= 1) {
        int u = (t >= off) ? lds[t - off] : 0;
        __syncthreads();
        lds[t] += u;
        __syncthreads();
    }
    int n0 = b << 8;
    int ex = eb + lds[t] - v;
    if (n0 + t < N_NODES) {
        indeg[n0 + t] = v;
        rowptr[n0 + t] = ex;
    }
    curs[t] = ex;
    __syncthreads();
    for (int e = eb + t; e < ee; e += 256) {
        uint2 ed = bufD[e];
        int slot = atomicAdd(&curs[ed.x & 255], 1);
        csr_src[slot] = (int)ed.y;
    }
}

// ---- K5: per src-bucket: outdeg histogram + fused n_feat prescale -> Xs bf16 ----
__global__ __launch_bounds__(256) void k5_outdeg_prescale(const int* __restrict__ bufS,
        const int* __restrict__ baseS, const float* __restrict__ n_feat,
        int* __restrict__ outdeg, unsigned int* __restrict__ Xs) {
    __shared__ int cnt[256];
    __shared__ float od[256];
    int b = blockIdx.x, t = threadIdx.x;
    int eb = baseS[b], ee = baseS[b + 1];
    cnt[t] = 0;
    __syncthreads();
    for (int e = eb + t; e < ee; e += 256)
        atomicAdd(&cnt[bufS[e] & 255], 1);
    __syncthreads();
    int n0 = b << 8;
    int nn = min(256, N_NODES - n0);
    if (t < nn) outdeg[n0 + t] = cnt[t];
    od[t] = rsqrtf(fmaxf((float)cnt[t], 1.0f));
    __syncthreads();
    int pc = t & 127;       // pair-column
    int rh = t >> 7;        // row parity
    for (int r = rh; r < nn; r += 2) {
        int row = n0 + r;
        float2 v = *reinterpret_cast<const float2*>(n_feat + (size_t)row * 128 + pc * 2);
        float s = od[r];
        Xs[(size_t)row * 64 + pc] = pack2(v.x * s, v.y * s);
    }
}

// ---- pull aggregation: wave/node, paired rows, 8B/lane, scalar indices ----
// MODE 0: out = bf16(acc * id)
// MODE 1: out = bf16(relu(acc*id + bias) * od)   (pre-scales for next layer)
template<int MODE>
__global__ __launch_bounds__(256) void pull_agg(const unsigned int* __restrict__ X,
        const int* __restrict__ rowptr, const int* __restrict__ csr_src,
        const int* __restrict__ indeg, const int* __restrict__ outdeg,
        const float* __restrict__ bias, unsigned int* __restrict__ out) {
    int lane = threadIdx.x & 63;
    int n = blockIdx.x * 4 + (threadIdx.x >> 6);
    n = __builtin_amdgcn_readfirstlane(n);     // force SGPR: scalar loads below
    if (n >= N_NODES) return;
    int l32 = lane & 31;
    int half = lane >> 5;
    int beg = rowptr[n];
    int cnt = rowptr[n + 1] - beg;
    const int* ep = csr_src + beg;
    float a0 = 0.f, a1 = 0.f, a2 = 0.f, a3 = 0.f;
    int voff = l32 << 1;

    auto acc = [&](uint2 u) {
        a0 += bf2f((unsigned short)(u.x & 0xffff));
        a1 += bf2f((unsigned short)(u.x >> 16));
        a2 += bf2f((unsigned short)(u.y & 0xffff));
        a3 += bf2f((unsigned short)(u.y >> 16));
    };

    int j = 0;
    for (; j + 8 <= cnt; j += 8) {
        uint2 u[4];
#pragma unroll
        for (int q = 0; q < 4; q++) {
            int sa = ep[j + 2 * q], sb = ep[j + 2 * q + 1];
            int s = half ? sb : sa;
            u[q] = *reinterpret_cast<const uint2*>(X + ((size_t)s << 6) + voff);
        }
#pragma unroll
        for (int q = 0; q < 4; q++) acc(u[q]);
    }
    for (; j + 2 <= cnt; j += 2) {
        int sa = ep[j], sb = ep[j + 1];
        int s = half ? sb : sa;
        acc(*reinterpret_cast<const uint2*>(X + ((size_t)s << 6) + voff));
    }
    if (j < cnt && half == 0) {
        int s = ep[j];
        acc(*reinterpret_cast<const uint2*>(X + ((size_t)s << 6) + voff));
    }

    a0 += __shfl_xor(a0, 32);
    a1 += __shfl_xor(a1, 32);
    a2 += __shfl_xor(a2, 32);
    a3 += __shfl_xor(a3, 32);

    if (lane < 32) {
        float id = rsqrtf(fmaxf((float)indeg[n], 1.0f));
        float v0 = a0 * id, v1 = a1 * id, v2 = a2 * id, v3 = a3 * id;
        if (MODE == 1) {
            float odv = rsqrtf(fmaxf((float)outdeg[n], 1.0f));
            float4 bv = *reinterpret_cast<const float4*>(bias + l32 * 4);
            v0 = fmaxf(v0 + bv.x, 0.f) * odv;
            v1 = fmaxf(v1 + bv.y, 0.f) * odv;
            v2 = fmaxf(v2 + bv.z, 0.f) * odv;
            v3 = fmaxf(v3 + bv.w, 0.f) * odv;
        }
        uint2 o = make_uint2(pack2(v0, v1), pack2(v2, v3));
        *reinterpret_cast<uint2*>(out + (size_t)n * 64 + voff) = o;
    }
}

// ---------------- MFMA bf16 GEMM, B-resident-in-registers, A streamed ----------------
// out[M,NOUT] = A[M,K] @ W[K,NOUT].  WT: bf16 [NOUT][K] (= W^T).
// Each wave owns a 64-col slice (NBW = NOUT/64 16-col blocks), preloads all its
// B fragments into registers once, then grid-strides over 16-row A tiles.
// N_NODES = 3125 * 16 exactly -> no row bounds checks.
// EPI 1: bias+relu (aux=bias[NOUT])   EPI 2: row-scale by rsqrt(outdeg) (auxi=outdeg)
template<int K, int NOUT, int EPI>
__global__ __launch_bounds__(256) void mfma_gemm(const unsigned short* __restrict__ A,
        const unsigned short* __restrict__ WT, const float* __restrict__ aux,
        const int* __restrict__ auxi, unsigned short* __restrict__ out) {
    constexpr int KK  = K / 32;      // MFMA k-steps
    constexpr int NBW = NOUT / 64;   // 16-col blocks per wave (4 or 2)
    int wave = threadIdx.x >> 6;
    int lane = threadIdx.x & 63;
    int col0 = lane & 15;
    int kgrp = (lane >> 4) * 8;
    int wcol = wave * NBW * 16;

    // B fragments: resident for the whole kernel (statically indexed -> registers)
    short8_t b[NBW][KK];
    {
        const unsigned short* wbase = WT + (size_t)(wcol + col0) * K + kgrp;
#pragma unroll
        for (int n = 0; n < NBW; n++)
#pragma unroll
            for (int kk = 0; kk < KK; kk++)
                b[n][kk] = *reinterpret_cast<const short8_t*>(
                    wbase + (size_t)n * 16 * K + kk * 32);
    }
    float bv[NBW];
    if (EPI == 1) {
#pragma unroll
        for (int n = 0; n < NBW; n++) bv[n] = aux[wcol + n * 16 + col0];
    }

    constexpr int NT = N_NODES / 16;   // 3125 row tiles, exact
    for (int rt = blockIdx.x; rt < NT; rt += gridDim.x) {
        const unsigned short* ap = A + (size_t)(rt * 16 + col0) * K + kgrp;
        short8_t a[KK];
#pragma unroll
        for (int kk = 0; kk < KK; kk++)
            a[kk] = *reinterpret_cast<const short8_t*>(ap + kk * 32);

        f32x4 acc[NBW];
#pragma unroll
        for (int n = 0; n < NBW; n++) acc[n] = f32x4{0.f, 0.f, 0.f, 0.f};
#pragma unroll
        for (int kk = 0; kk < KK; kk++)
#pragma unroll
            for (int n = 0; n < NBW; n++)
                acc[n] = __builtin_amdgcn_mfma_f32_16x16x32_bf16(a[kk], b[n][kk], acc[n], 0, 0, 0);

        // C/D layout: col = lane&15, row = (lane>>4)*4 + reg
        int rbase = rt * 16 + ((lane >> 4) << 2);
        float rs[4];
        if (EPI == 2) {
#pragma unroll
            for (int j = 0; j < 4; j++)
                rs[j] = rsqrtf(fmaxf((float)auxi[rbase + j], 1.0f));
        }
#pragma unroll
        for (int n = 0; n < NBW; n++) {
            int col = wcol + n * 16 + col0;
#pragma unroll
            for (int j = 0; j < 4; j++) {
                float v = acc[n][j];
                if (EPI == 1) v = fmaxf(v + bv[n], 0.f);
                if (EPI == 2) v = v * rs[j];
                out[(size_t)(rbase + j) * NOUT + col] = f2bf(v);
            }
        }
    }
}

// ---------------- sum pooling over contiguous segments (bf16x2 loads) ----------
__global__ __launch_bounds__(512) void seg_pool(const unsigned int* __restrict__ X,
        const int* __restrict__ gstart, float* __restrict__ emb) {
    int g = blockIdx.x;
    int lane = threadIdx.x & 63;
    int stripe = threadIdx.x >> 6;
    int beg = gstart[g], end = gstart[g + 1];
    float ax = 0.f, ay = 0.f;
    for (int r = beg + stripe; r < end; r += 8) {
        unsigned u = X[(size_t)r * 64 + lane];
        ax += bf2f((unsigned short)(u & 0xffff));
        ay += bf2f((unsigned short)(u >> 16));
    }
    __shared__ float bufx[8][64], bufy[8][64];
    bufx[stripe][lane] = ax;
    bufy[stripe][lane] = ay;
    __syncthreads();
    if (stripe == 0) {
        float sx = 0.f, sy = 0.f;
#pragma unroll
        for (int q = 0; q < 8; q++) { sx += bufx[q][lane]; sy += bufy[q][lane]; }
        emb[g * 128 + lane * 2]     = sx;
        emb[g * 128 + lane * 2 + 1] = sy;
    }
}

// ---------------- fused BN + FC head + log_softmax ----------------
__global__ __launch_bounds__(128) void fc_kernel(const float* __restrict__ emb,
        const float* __restrict__ gamma, const float* __restrict__ beta,
        const float* __restrict__ Wf1, const float* __restrict__ bf1,
        const float* __restrict__ Wf2, const float* __restrict__ bf2,
        float* __restrict__ out_ls) {
    __shared__ float h[H2];
    __shared__ float logits[OUT_DIM];
    int g = blockIdx.x;
    int j = threadIdx.x;
    float s = 0.f;
    for (int q = 0; q < N_GRAPHS; q++) s += emb[q * 128 + j];
    float mean = s * (1.0f / N_GRAPHS);
    float v = 0.f;
    for (int q = 0; q < N_GRAPHS; q++) {
        float d = emb[q * 128 + j] - mean;
        v += d * d;
    }
    v *= (1.0f / N_GRAPHS);
    float scale = rsqrtf(v + BN_EPS) * gamma[j];
    h[j] = (emb[g * 128 + j] - mean) * scale + beta[j];
    __syncthreads();
    float acc = bf1[j];
    for (int k = 0; k < H2; k++) acc += h[k] * Wf1[k * H2 + j];
    __syncthreads();
    h[j] = fmaxf(acc, 0.f);
    __syncthreads();
    if (j < OUT_DIM) {
        float a2 = bf2[j];
        for (int k = 0; k < H2; k++) a2 += h[k] * Wf2[k * OUT_DIM + j];
        logits[j] = a2;
    }
    __syncthreads();
    if (j < OUT_DIM) {
        float m = -1e30f;
        for (int o = 0; o < OUT_DIM; o++) m = fmaxf(m, logits[o]);
        float se = 0.f;
        for (int o = 0; o < OUT_DIM; o++) se += expf(logits[o] - m);
        out_ls[g * OUT_DIM + j] = logits[j] - m - logf(se);
    }
}

extern "C" void kernel_launch(void* const* d_in, const int* in_sizes, int n_in,
                              void* d_out, int out_size, void* d_ws, size_t ws_size,
                              hipStream_t stream) {
    const float* n_feat = (const float*)d_in[0];
    const int*   src    = (const int*)d_in[1];
    const int*   dst    = (const int*)d_in[2];
    const int*   gid    = (const int*)d_in[3];
    const float* W1     = (const float*)d_in[4];
    const float* b1     = (const float*)d_in[5];
    const float* W2     = (const float*)d_in[6];
    const float* b2     = (const float*)d_in[7];
    const float* W3     = (const float*)d_in[8];
    const float* b3     = (const float*)d_in[9];
    const float* Wf1    = (const float*)d_in[10];
    const float* bf1    = (const float*)d_in[11];
    const float* Wf2    = (const float*)d_in[12];
    const float* bf2    = (const float*)d_in[13];
    const float* gamma  = (const float*)d_in[14];
    const float* beta   = (const float*)d_in[15];
    float* out = (float*)d_out;

    char* ws = (char*)d_ws;
    size_t off = 0;
    auto alloc = [&](size_t bytes) {
        void* p = ws + off;
        off = (off + bytes + 255) & ~(size_t)255;
        return p;
    };
    int* cntD    = (int*)alloc((size_t)NB_EDGE * 256 * 4);
    int* cntS    = (int*)alloc((size_t)NB_EDGE * 256 * 4);
    int* offD    = (int*)alloc((size_t)NB_EDGE * 256 * 4);
    int* offS    = (int*)alloc((size_t)NB_EDGE * 256 * 4);
    int* baseD   = (int*)alloc(257 * 4);
    int* baseS   = (int*)alloc(257 * 4);
    int* indeg   = (int*)alloc((size_t)N_NODES * 4);
    int* outdeg  = (int*)alloc((size_t)N_NODES * 4);
    int* rowptr  = (int*)alloc((size_t)(N_NODES + 1) * 4);
    int* gstart  = (int*)alloc((size_t)(N_GRAPHS + 1) * 4);
    uint2* bufD  = (uint2*)alloc((size_t)N_EDGES * 8);
    int* bufS    = (int*)alloc((size_t)N_EDGES * 4);
    int* csr_src = (int*)alloc((size_t)N_EDGES * 4);
    unsigned short* Xs  = (unsigned short*)alloc((size_t)N_NODES * 128 * 2);
    unsigned short* A   = (unsigned short*)alloc((size_t)N_NODES * 128 * 2);
    unsigned short* B   = (unsigned short*)alloc((size_t)N_NODES * 256 * 2);
    unsigned short* W1T = (unsigned short*)alloc((size_t)IN_DIM * HID * 2);
    unsigned short* W2T = (unsigned short*)alloc((size_t)HID * H2 * 2);
    unsigned short* W3T = (unsigned short*)alloc((size_t)H2 * H2 * 2);

    // preprocessing: zero global atomics
    k1_hist<<<NB_EDGE + CW1_BLOCKS + CW2_BLOCKS + CW3_BLOCKS + BND_BLOCKS, 256, 0, stream>>>(
        src, dst, cntD, cntS, W1, W2, W3, W1T, W2T, W3T, gid, gstart);
    k2_scan<<<1, 256, 0, stream>>>(cntD, cntS, offD, offS, baseD, baseS, rowptr);
    k3_scatter<<<NB_EDGE, 256, 0, stream>>>(src, dst, offD, offS, baseD, baseS, bufD, bufS);
    k4_csr<<<NBUCK, 256, 0, stream>>>(bufD, baseD, indeg, rowptr, csr_src);
    k5_outdeg_prescale<<<NBUCK, 256, 0, stream>>>(bufS, baseS, n_feat, outdeg,
                                                  (unsigned int*)Xs);

    const int AGG_GRID = (N_NODES + 3) / 4;
    const int GEMM_GRID = 1024;

    // Layer 1: A = bf16(agg(Xs)·id); B = bf16(relu(A@W1 + b1))  [N,256]
    pull_agg<0><<<AGG_GRID, 256, 0, stream>>>((unsigned int*)Xs, rowptr, csr_src,
                                              indeg, outdeg, nullptr, (unsigned int*)A);
    mfma_gemm<128, 256, 1><<<GEMM_GRID, 256, 0, stream>>>(A, W1T, b1, nullptr, B);

    // Layer 2: A = bf16((X1@W2)·od); B = bf16(relu(agg(A)·id + b2)·od)
    mfma_gemm<256, 128, 2><<<GEMM_GRID, 256, 0, stream>>>(B, W2T, nullptr, outdeg, A);
    pull_agg<1><<<AGG_GRID, 256, 0, stream>>>((unsigned int*)A, rowptr, csr_src,
                                              indeg, outdeg, b2, (unsigned int*)B);

    // Layer 3: A = bf16(agg(B)·id); B = bf16(relu(A@W3 + b3))
    pull_agg<0><<<AGG_GRID, 256, 0, stream>>>((unsigned int*)B, rowptr, csr_src,
                                              indeg, outdeg, nullptr, (unsigned int*)A);
    mfma_gemm<128, 128, 1><<<GEMM_GRID, 256, 0, stream>>>(A, W3T, b3, nullptr, B);

    // Readout
    seg_pool<<<N_GRAPHS, 512, 0, stream>>>((unsigned int*)B, gstart, out);
    fc_kernel<<<N_GRAPHS, 128, 0, stream>>>(out, gamma, beta, Wf1, bf1, Wf2, bf2,
                                            out + (size_t)N_GRAPHS * H2);
}